// Round 11
// baseline (275.564 us; speedup 1.0000x reference)
//
#include <hip/hip_runtime.h>

// ---------------------------------------------------------------------------
// Bidirectional Mamba block, MI355X. Round 31:
//  - REVERT R30 ring prefetch (regression: +11us on kscanC, VGPR 28->44 with
//    no better load schedule; compiler's schedule was already fine).
//  - kscanC: DPP rowsum (8 of 15 inst/step, result used by 1 of 16 lanes)
//    replaced by DEFERRED reduction: main loop stores h to LDS (1 contiguous
//    ds_write); per 32-step half, a coop pass multiplies by C (from staged
//    bl), sums 16, adds D-term, writes y to global. ~6 VALU + 2 DS per step.
//    LDS 12.8 -> 43 KB (3 blocks/CU); ILP covers the lower occupancy.
//  - kscanA: P = exp(A*sum(dv)) (identical math, kills serial P-mult chain).
// Shapes: B=4, C=64, D=128, L=4096 (l = h*256 + w*16 + t), N=16, R=8.
// ---------------------------------------------------------------------------

#define NL 4096

typedef unsigned short u16;
typedef unsigned int u32;
typedef __attribute__((ext_vector_type(8))) short bf16x8;
typedef __attribute__((ext_vector_type(4))) float f32x4;

__device__ __forceinline__ float siluf_(float x) {
  return x * __builtin_amdgcn_rcpf(1.f + __expf(-x));
}
__device__ __forceinline__ float softplusf_(float x) {
  return (x > 20.f) ? x : __logf(1.f + __expf(x));
}
__device__ __forceinline__ u16 f2bf(float f) {
  u32 u = __float_as_uint(f);
  u += 0x7fffu + ((u >> 16) & 1u);
  return (u16)(u >> 16);
}

// Per-b slab offsets (fp32 elements)
#define OXZ  0u          // xz [256][4096] fp32
#define OUCF 1048576u    // ucf [128][4096] fp32
#define OUCB 1572864u    // ucb [128][4096] fp32 (flipped coords)
#define ODLF 2424832u    // dlf [128][4096] fp32
#define ODLB 2949120u    // dlb [128][4096] fp32 (flipped coords)
#define OYF  3473408u    // yf [128][4096] fp32
#define OYB  3997696u    // yb [128][4096] fp32 (flipped coords)
#define OO   4521984u    // scan scratch: P [262144] S [262144] fp32
#define OO2  5046272u    // bct bf16 until kscanC; then o2 [4096][64] fp32
#define PER_B 5570560u
// Wbf8 [8 xcd][27][64][64] bf16 lives at ws + bcnt*PER_B

#define NCH 64   // scan chunks
#define CL  64   // chunk length
#define WB1 110592u  // u16 elems per Wbf copy (27*64*64)

// 1. xz[e,l] = sum_c in_proj_w[e,c] * seq[c,l].
__global__ __launch_bounds__(256) void kxz(
    const float* __restrict__ x, const float* __restrict__ wip,
    float* __restrict__ ws, int b0) {
  int bi = blockIdx.y, gb = b0 + bi;
  float* s = ws + (size_t)bi * PER_B;
  int bid = blockIdx.x;
  int h = bid >> 4, w = bid & 15;
  int tid = threadIdx.x;
  __shared__ float xs[64][16];
  for (int i = tid; i < 1024; i += 256) {
    int c = i >> 4, t = i & 15;
    xs[c][t] = x[(size_t)(gb * 64 + c) * NL + t * 256 + h * 16 + w];
  }
  __syncthreads();
  int e = tid;
  float acc[16];
#pragma unroll
  for (int t = 0; t < 16; ++t) acc[t] = 0.f;
  for (int c = 0; c < 64; ++c) {
    float wv = wip[e * 64 + c];
#pragma unroll
    for (int t = 0; t < 16; ++t) acc[t] = fmaf(wv, xs[c][t], acc[t]);
  }
  float4* dst = (float4*)(s + OXZ + (size_t)e * NL + h * 256 + w * 16);
#pragma unroll
  for (int q = 0; q < 4; ++q)
    dst[q] = make_float4(acc[q * 4], acc[q * 4 + 1], acc[q * 4 + 2], acc[q * 4 + 3]);
}

// 2. Fused prep per (bi, dir, 32-l tile): dwconv+silu, x_dbl via MFMA, delta,
// bct. Grid x = 256 (lt 128 x dir 2). uc/dl stored fp32.
__global__ __launch_bounds__(256) void k2prep(
    const float* __restrict__ cwf, const float* __restrict__ cbf,
    const float* __restrict__ xpf, const float* __restrict__ dtwf,
    const float* __restrict__ dtbf,
    const float* __restrict__ cwb, const float* __restrict__ cbb,
    const float* __restrict__ xpb, const float* __restrict__ dtwb,
    const float* __restrict__ dtbb,
    float* __restrict__ ws) {
  int bi = blockIdx.y;
  float* s = ws + (size_t)bi * PER_B;
  int bx = blockIdx.x;
  int lt = bx >> 1, dir = bx & 1;
  int l0 = lt * 32;
  int lout0 = dir ? (127 - lt) * 32 : l0;   // output base (flipped for bwd)
  int tid = threadIdx.x;

  __shared__ float pool[128 * 40];   // X[128][40] during dwconv; xds after
  __shared__ u16 uct[32][136];       // uc transposed bf16 (d-contig, 16B rows)
  float (*X)[40] = (float(*)[40])pool;

  for (int i = tid; i < 128 * 38; i += 256) {
    int d = i / 38, j = i - d * 38;
    int l = l0 - 3 + j;
    X[d][j] = (l >= 0 && l < NL) ? s[OXZ + (size_t)d * NL + l] : 0.f;
  }
  __syncthreads();

  const float* cw = dir ? cwb : cwf;
  const float* cb = dir ? cbb : cbf;
  float* ucg = s + (dir ? OUCB : OUCF);
  for (int i = tid; i < 128 * 32; i += 256) {
    int d = i >> 5, li = i & 31;
    float a = cb[d];
    if (dir == 0) {
#pragma unroll
      for (int k = 0; k < 4; ++k) a = fmaf(cw[d * 4 + k], X[d][li + k], a);
    } else {
#pragma unroll
      for (int k = 0; k < 4; ++k) a = fmaf(cw[d * 4 + k], X[d][37 - li - k], a);
    }
    a = siluf_(a);
    uct[li][d] = f2bf(a);
    ucg[(size_t)d * NL + lout0 + li] = a;
  }
  __syncthreads();  // X dead; pool becomes xds [40][33]

  // x_dbl via MFMA 16x16x32: D[e 48][l 32], K=128. Units (et,lt2) = 6 over
  // 4 waves (waves 0,1 take two units).
  float* xds = pool;
  {
    int wid = tid >> 6, lane = tid & 63;
    int n16 = lane & 15, kg = lane >> 4;
    const float* xp = dir ? xpb : xpf;
#pragma unroll
    for (int rep = 0; rep < 2; ++rep) {
      int id = wid + rep * 4;
      if (id < 6) {
        int et = id >> 1, lt2 = id & 1;
        f32x4 acc = {};
#pragma unroll
        for (int ks = 0; ks < 4; ++ks) {
          bf16x8 bfrag = *(const bf16x8*)&uct[lt2 * 16 + n16][ks * 32 + kg * 8];
          int e = et * 16 + n16;
          int ec = (e < 40) ? e : 39;        // clamp addr; rows >=40 discarded
          const float* pa = xp + ec * 128 + ks * 32 + kg * 8;
          float4 a0 = *(const float4*)pa;
          float4 a1 = *(const float4*)(pa + 4);
          bf16x8 af;
          af[0] = (short)f2bf(a0.x); af[1] = (short)f2bf(a0.y);
          af[2] = (short)f2bf(a0.z); af[3] = (short)f2bf(a0.w);
          af[4] = (short)f2bf(a1.x); af[5] = (short)f2bf(a1.y);
          af[6] = (short)f2bf(a1.z); af[7] = (short)f2bf(a1.w);
          acc = __builtin_amdgcn_mfma_f32_16x16x32_bf16(af, bfrag, acc, 0, 0, 0);
        }
        // D layout: col = lane&15 (l), row = kg*4 + rg (e within 16-tile)
#pragma unroll
        for (int rg = 0; rg < 4; ++rg) {
          int e = et * 16 + kg * 4 + rg;
          if (e < 40) xds[e * 33 + lt2 * 16 + n16] = acc[rg];
        }
      }
    }
  }
  __syncthreads();

  const float* dtw = dir ? dtwb : dtwf;
  const float* dtb = dir ? dtbb : dtbf;
  float* dlg = s + (dir ? ODLB : ODLF);
  for (int i = tid; i < 128 * 32; i += 256) {
    int d = i >> 5, li = i & 31;
    float pre = dtb[d];
#pragma unroll
    for (int r = 0; r < 8; ++r)
      pre = fmaf(dtw[d * 8 + r], xds[r * 33 + li], pre);
    dlg[(size_t)d * NL + lout0 + li] = softplusf_(pre);
  }
  u16* bctp = (u16*)(s + OO2);
  for (int i = tid; i < 32 * 32; i += 256) {
    int li = i >> 5, k = i & 31;
    bctp[((size_t)dir * 4096 + lout0 + li) * 32 + k] = f2bf(xds[(8 + k) * 33 + li]);
  }
}

// 5a. Phase A: 16 d-rows/block; B-half of bct staged to fp32 LDS; fp32 dl/uc
// float4 loads (R29 form); P via exp(A*sum(dv)) - no serial P-mult chain.
__global__ __launch_bounds__(256) void kscanA(
    const float* __restrict__ Alf, const float* __restrict__ Alb,
    float* __restrict__ ws) {
  int bi = blockIdx.y;
  float* s = ws + (size_t)bi * PER_B;
  int xid = blockIdx.x;
  int chunk = xid >> 4, dir = (xid >> 3) & 1, d8 = xid & 7;
  int tid = threadIdx.x;
  int wv = tid >> 6, lane = tid & 63;
  int n = lane & 15, g = lane >> 4;
  int d = d8 * 16 + wv * 4 + g;
  int l0 = chunk * CL;
  __shared__ float bl[CL * 16];
  {
    const u16* bctp = (const u16*)(s + OO2) + ((size_t)dir * 4096 + l0) * 32;
    for (int i = tid; i < CL * 16; i += 256) {
      int l = i >> 4, k = i & 15;
      bl[i] = __uint_as_float(((u32)bctp[l * 32 + k]) << 16);
    }
  }
  __syncthreads();
  const float* ucp = s + (dir ? OUCB : OUCF) + (size_t)d * NL + l0;
  const float* dlp = s + (dir ? ODLB : ODLF) + (size_t)d * NL + l0;
  const float* blB = bl + n;
  float A = -__expf((dir ? Alb : Alf)[d * 16 + n]);
  float sdv = 0.f, S = 0.f;
#pragma unroll
  for (int i0 = 0; i0 < CL; i0 += 8) {
    float4 dq0 = *(const float4*)(dlp + i0);
    float4 dq1 = *(const float4*)(dlp + i0 + 4);
    float4 uq0 = *(const float4*)(ucp + i0);
    float4 uq1 = *(const float4*)(ucp + i0 + 4);
    float dv[8] = {dq0.x, dq0.y, dq0.z, dq0.w, dq1.x, dq1.y, dq1.z, dq1.w};
    float uv[8] = {uq0.x, uq0.y, uq0.z, uq0.w, uq1.x, uq1.y, uq1.z, uq1.w};
#pragma unroll
    for (int j = 0; j < 8; ++j) {
      float dA = __expf(dv[j] * A);
      S = fmaf(dA, S, dv[j] * blB[(i0 + j) * 16] * uv[j]);
      sdv += dv[j];
    }
  }
  size_t cidx = ((size_t)(chunk * 2 + dir) * 128 + d) * 16 + n;
  s[OO + cidx] = __expf(A * sdv);
  s[OO + 262144u + cidx] = S;
}

// 5c. Phase C: self-seeded re-scan with DEFERRED C-reduction: main loop
// stores h to LDS (contiguous ds_write); per 32-step half a coop pass does
// y = sum_n C[l,n]*h[l,n] + uc*Dv and writes global directly.
__global__ __launch_bounds__(256) void kscanC(
    const float* __restrict__ Alf, const float* __restrict__ Df,
    const float* __restrict__ Alb, const float* __restrict__ Db,
    float* __restrict__ ws) {
  int bi = blockIdx.y;
  float* s = ws + (size_t)bi * PER_B;
  int xid = blockIdx.x;
  int chunk = xid >> 4, dir = (xid >> 3) & 1, d8 = xid & 7;
  int tid = threadIdx.x;
  int wv = tid >> 6, lane = tid & 63;
  int n = lane & 15, g = lane >> 4;
  int d = d8 * 16 + wv * 4 + g;
  int l0 = chunk * CL;
  __shared__ float bl[CL * 32];          // 8 KB: B at [l][0..16), C at [l][16..32)
  __shared__ float Chw[4][32][68];       // 34.8 KB: per-wave h staging
  {
    const u16* bctp = (const u16*)(s + OO2) + ((size_t)dir * 4096 + l0) * 32;
    for (int i = tid; i < CL * 32; i += 256)
      bl[i] = __uint_as_float(((u32)bctp[i]) << 16);
  }
  // Self-seed: fold P/S of chunks < chunk for this (dir, d, n).
  float h = 0.f;
  {
    size_t stepi = (size_t)d * 16 + n;
#pragma unroll 4
    for (int c = 0; c < chunk; ++c) {
      size_t idx = ((size_t)(c * 2 + dir) * 128) * 16 + stepi;
      float pv = s[OO + idx], sv = s[OO + 262144u + idx];
      h = fmaf(pv, h, sv);
    }
  }
  __syncthreads();
  const float* ucp = s + (dir ? OUCB : OUCF) + (size_t)d * NL + l0;
  const float* dlp = s + (dir ? ODLB : ODLF) + (size_t)d * NL + l0;
  const float* ucb0 = s + (dir ? OUCB : OUCF) + l0;   // base without d offset
  const float* blB = bl + n;
  float* ybase = s + (dir ? OYB : OYF);
  const float* Dvp = dir ? Db : Df;
  float A = -__expf((dir ? Alb : Alf)[d * 16 + n]);

#pragma unroll
  for (int H = 0; H < 2; ++H) {
#pragma unroll
    for (int i0b = 0; i0b < 32; i0b += 8) {
      int i0 = H * 32 + i0b;
      float4 dq0 = *(const float4*)(dlp + i0);
      float4 dq1 = *(const float4*)(dlp + i0 + 4);
      float4 uq0 = *(const float4*)(ucp + i0);
      float4 uq1 = *(const float4*)(ucp + i0 + 4);
      float dv[8] = {dq0.x, dq0.y, dq0.z, dq0.w, dq1.x, dq1.y, dq1.z, dq1.w};
      float uv[8] = {uq0.x, uq0.y, uq0.z, uq0.w, uq1.x, uq1.y, uq1.z, uq1.w};
      float hv[8];
#pragma unroll
      for (int j = 0; j < 8; ++j) {
        float dA = __expf(dv[j] * A);
        h = fmaf(dA, h, dv[j] * blB[(i0 + j) * 32] * uv[j]);
        hv[j] = h;
      }
#pragma unroll
      for (int j = 0; j < 8; ++j) Chw[wv][i0b + j][g * 16 + n] = hv[j];
    }
    __syncthreads();
    // Coop reduction: 512 outputs (wv_o, g_o, l_o), 2 per thread.
#pragma unroll
    for (int rep = 0; rep < 2; ++rep) {
      int o = tid + rep * 256;
      int l_o = o & 31, g_o = (o >> 5) & 3, wv_o = o >> 7;
      int lc = H * 32 + l_o;             // l within chunk
      const float* hrow = &Chw[wv_o][l_o][g_o * 16];
      const float* crow = &bl[lc * 32 + 16];
      float y = 0.f;
#pragma unroll
      for (int q = 0; q < 4; ++q) {
        float4 h4 = *(const float4*)(hrow + q * 4);
        float4 c4 = *(const float4*)(crow + q * 4);
        y = fmaf(h4.x, c4.x, y); y = fmaf(h4.y, c4.y, y);
        y = fmaf(h4.z, c4.z, y); y = fmaf(h4.w, c4.w, y);
      }
      int d_o = d8 * 16 + wv_o * 4 + g_o;
      float u = ucb0[(size_t)d_o * NL + lc];
      y = fmaf(u, Dvp[d_o], y);
      ybase[(size_t)d_o * NL + l0 + lc] = y;
    }
    __syncthreads();
  }
}

// 6. Fused gate + out-proj via MFMA. Block = 32-l tile.
__global__ __launch_bounds__(256) void koutg(
    const float* __restrict__ wout, float* __restrict__ ws) {
  int bi = blockIdx.y;
  float* s = ws + (size_t)bi * PER_B;
  int lt = blockIdx.x;
  int l0 = lt * 32;
  int tid = threadIdx.x;
  __shared__ u16 otb[32][136];
  for (int i = tid; i < 128 * 32; i += 256) {
    int d = i >> 5, li = i & 31;
    int l = l0 + li;
    float z = s[OXZ + (size_t)(128 + d) * NL + l];
    float v = s[OYF + (size_t)d * NL + l] + s[OYB + (size_t)d * NL + (NL - 1 - l)];
    otb[li][d] = f2bf(v * siluf_(z));
  }
  __syncthreads();
  int wid = tid >> 6, lane = tid & 63;
  int n16 = lane & 15, kg = lane >> 4;
  f32x4 acc[2] = {};   // [l2 tile]
  const float* wr = wout + (size_t)(wid * 16 + n16) * 128 + kg * 8;
#pragma unroll
  for (int ks = 0; ks < 4; ++ks) {
    const float* pa = wr + ks * 32;
    float4 a0 = *(const float4*)pa;
    float4 a1 = *(const float4*)(pa + 4);
    bf16x8 af;
    af[0] = (short)f2bf(a0.x); af[1] = (short)f2bf(a0.y);
    af[2] = (short)f2bf(a0.z); af[3] = (short)f2bf(a0.w);
    af[4] = (short)f2bf(a1.x); af[5] = (short)f2bf(a1.y);
    af[6] = (short)f2bf(a1.z); af[7] = (short)f2bf(a1.w);
    bf16x8 b0 = *(const bf16x8*)&otb[n16][ks * 32 + kg * 8];
    bf16x8 b1 = *(const bf16x8*)&otb[16 + n16][ks * 32 + kg * 8];
    acc[0] = __builtin_amdgcn_mfma_f32_16x16x32_bf16(af, b0, acc[0], 0, 0, 0);
    acc[1] = __builtin_amdgcn_mfma_f32_16x16x32_bf16(af, b1, acc[1], 0, 0, 0);
  }
  // D: col = lane&15 (l), row = kg*4+rg (c in 16-tile); rg = consecutive c.
#pragma unroll
  for (int l2 = 0; l2 < 2; ++l2) {
    float4 st = make_float4(acc[l2][0], acc[l2][1], acc[l2][2], acc[l2][3]);
    *(float4*)&s[OO2 + (size_t)(l0 + l2 * 16 + n16) * 64 + wid * 16 + kg * 4] = st;
  }
}

// 6.5. Weight prep: Wbf8[xcd 8][27][co 64][ci 64] bf16 at ws + bcnt*PER_B.
__global__ __launch_bounds__(256) void kprepw(
    const float* __restrict__ pw, float* __restrict__ wdst) {
  int off = blockIdx.x;
  u16* wb = (u16*)wdst;
  int tid = threadIdx.x;
  for (int i = tid; i < 4096; i += 256) {
    int co = i >> 6, ci = i & 63;
    u16 v = f2bf(pw[(size_t)(co * 64 + ci) * 27 + off]);
#pragma unroll
    for (int xc = 0; xc < 8; ++xc)
      wb[(size_t)xc * WB1 + off * 4096 + i] = v;
  }
}

// 7. conv3d (bf16 implicit GEMM on MFMA) + FUSED 1x1x1 norm mix. (R27 form.)
__global__ __launch_bounds__(256, 2) void kconv3(
    const float* __restrict__ pb, const float* __restrict__ nw,
    const float* __restrict__ nb, const float* __restrict__ xin,
    float* __restrict__ out, const u16* __restrict__ wb,
    float* __restrict__ ws, int b0) {
  int bi = blockIdx.y, gb = b0 + bi;
  float* s = ws + (size_t)bi * PER_B;
  int bx = blockIdx.x;
  int t = bx >> 3, hq = bx & 7;
  int h0 = hq * 2;
  int tid = threadIdx.x;
  const float* xr = s + OO2;              // o2 in c-major reshape view

  __shared__ u16 Xs[3 * 4 * 18 * 72];     // 31104 B; later aliased as cx
  float* cx = (float*)Xs;                 // cx[64][33] = 8448 B
  {
    u32* xz32 = (u32*)Xs;
    for (int i = tid; i < 3 * 4 * 18 * 72 / 2; i += 256) xz32[i] = 0u;
  }
  __syncthreads();
  {
    int ci = tid >> 2, wq = tid & 3;
#pragma unroll
    for (int rowc = 0; rowc < 12; ++rowc) {
      int tt = rowc >> 2, hh = rowc & 3;
      int ts = t + tt - 1, hs = h0 + hh - 1;
      if (ts < 0 || ts > 15 || hs < 0 || hs > 15) continue;
      float4 v = *(const float4*)(xr + (size_t)ci * NL + ts * 256 + hs * 16 + wq * 4);
      int rb = (tt * 4 + hh) * 18 + 1 + wq * 4;
      Xs[(rb + 0) * 72 + ci] = f2bf(v.x);
      Xs[(rb + 1) * 72 + ci] = f2bf(v.y);
      Xs[(rb + 2) * 72 + ci] = f2bf(v.z);
      Xs[(rb + 3) * 72 + ci] = f2bf(v.w);
    }
  }
  __syncthreads();

  int wid = tid >> 6, lane = tid & 63;
  int cq = wid;
  int n16 = lane & 15, kg = lane >> 4;
  f32x4 acc[2] = {};

  const u16* wbA = wb + (size_t)(bx & 7) * WB1 +
                   (size_t)(cq * 16 + n16) * 64 + kg * 8;
#pragma unroll
  for (int kt = 0; kt < 3; ++kt)
#pragma unroll
    for (int kh = 0; kh < 3; ++kh) {
#pragma unroll
      for (int kw = 0; kw < 3; ++kw) {
        int off = (kt * 3 + kh) * 3 + kw;
        const u16* pa = wbA + off * 4096;
#pragma unroll
        for (int st = 0; st < 2; ++st) {
          int kb = st * 32;
          bf16x8 a0 = *(const bf16x8*)(pa + kb);
#pragma unroll
          for (int l2 = 0; l2 < 2; ++l2) {
            int r = (kt * 4 + l2 + kh) * 18 + n16 + kw;
            bf16x8 b0 = *(const bf16x8*)(&Xs[r * 72 + kb + kg * 8]);
            acc[l2] = __builtin_amdgcn_mfma_f32_16x16x32_bf16(a0, b0, acc[l2], 0, 0, 0);
          }
        }
      }
    }
  __syncthreads();

#pragma unroll
  for (int l2 = 0; l2 < 2; ++l2) {
    int lp = l2 * 16 + n16;
    int lg = t * 256 + (h0 + l2) * 16 + n16;
#pragma unroll
    for (int rg = 0; rg < 4; ++rg) {
      int co = cq * 16 + kg * 4 + rg;
      cx[co * 33 + lp] = acc[l2][rg] + pb[co] +
                         xin[(size_t)(gb * 64 + co) * NL + lg];
    }
  }
  __syncthreads();

  {
    int co2 = tid >> 2, pq = tid & 3;
    float mac[8];
#pragma unroll
    for (int j = 0; j < 8; ++j) mac[j] = 0.f;
    for (int ci = 0; ci < 64; ci += 4) {
      float4 w4 = *(const float4*)&nw[co2 * 64 + ci];
      float wv[4] = {w4.x, w4.y, w4.z, w4.w};
#pragma unroll
      for (int cc = 0; cc < 4; ++cc) {
        const float* row = &cx[(ci + cc) * 33 + pq * 8];
        float4 a = *(const float4*)&row[0];
        float4 b = *(const float4*)&row[4];
        mac[0] = fmaf(wv[cc], a.x, mac[0]);  mac[1] = fmaf(wv[cc], a.y, mac[1]);
        mac[2] = fmaf(wv[cc], a.z, mac[2]);  mac[3] = fmaf(wv[cc], a.w, mac[3]);
        mac[4] = fmaf(wv[cc], b.x, mac[4]);  mac[5] = fmaf(wv[cc], b.y, mac[5]);
        mac[6] = fmaf(wv[cc], b.z, mac[6]);  mac[7] = fmaf(wv[cc], b.w, mac[7]);
      }
    }
    float bias = nb[co2];
    float4* dst = (float4*)(out + (size_t)(gb * 64 + co2) * NL +
                            t * 256 + h0 * 16 + pq * 8);
    dst[0] = make_float4(mac[0] + bias, mac[1] + bias, mac[2] + bias, mac[3] + bias);
    dst[1] = make_float4(mac[4] + bias, mac[5] + bias, mac[6] + bias, mac[7] + bias);
  }
}

// ---------------------------------------------------------------------------
extern "C" void kernel_launch(void* const* d_in, const int* in_sizes, int n_in,
                              void* d_out, int out_size, void* d_ws, size_t ws_size,
                              hipStream_t stream) {
  const float* x    = (const float*)d_in[0];
  const float* wip  = (const float*)d_in[1];
  const float* cwf  = (const float*)d_in[2];
  const float* cbf  = (const float*)d_in[3];
  const float* xpf  = (const float*)d_in[4];
  const float* dtwf = (const float*)d_in[5];
  const float* dtbf = (const float*)d_in[6];
  const float* Alf  = (const float*)d_in[7];
  const float* Df   = (const float*)d_in[8];
  const float* cwb  = (const float*)d_in[9];
  const float* cbb  = (const float*)d_in[10];
  const float* xpb  = (const float*)d_in[11];
  const float* dtwb = (const float*)d_in[12];
  const float* dtbb = (const float*)d_in[13];
  const float* Alb  = (const float*)d_in[14];
  const float* Db   = (const float*)d_in[15];
  const float* wout = (const float*)d_in[16];
  const float* pw   = (const float*)d_in[17];
  const float* pb   = (const float*)d_in[18];
  const float* nw   = (const float*)d_in[19];
  const float* nb   = (const float*)d_in[20];

  const size_t PER_B_BYTES = (size_t)PER_B * 4;  // 22,282,240 per batch slab
  const size_t WB_BYTES = 8u * WB1 * 2u;         // 1,769,472 (8 Wbf replicas)
  int bcnt;
  if (ws_size >= 4 * PER_B_BYTES + WB_BYTES) bcnt = 4;
  else if (ws_size >= PER_B_BYTES + WB_BYTES) bcnt = 1;
  else return;
  int passes = 4 / bcnt;

  float* ws = (float*)d_ws;
  float* wsW = ws + (size_t)bcnt * PER_B;
  kprepw<<<dim3(27), 256, 0, stream>>>(pw, wsW);
  for (int p = 0; p < passes; ++p) {
    int b0 = p * bcnt;
    kxz   <<<dim3(256, bcnt), 256, 0, stream>>>(x, wip, ws, b0);
    k2prep<<<dim3(256, bcnt), 256, 0, stream>>>(cwf, cbf, xpf, dtwf, dtbf,
                                                cwb, cbb, xpb, dtwb, dtbb, ws);
    kscanA<<<dim3(1024, bcnt), 256, 0, stream>>>(Alf, Alb, ws);
    kscanC<<<dim3(1024, bcnt), 256, 0, stream>>>(Alf, Df, Alb, Db, ws);
    koutg <<<dim3(128, bcnt), 256, 0, stream>>>(wout, ws);
    kconv3<<<dim3(128, bcnt), 256, 0, stream>>>(pb, nw, nb, x, (float*)d_out,
                                                (const u16*)wsW, ws, b0);
  }
}

// Round 12
// 260.757 us; speedup vs baseline: 1.0568x; 1.0568x over previous
//
#include <hip/hip_runtime.h>

// ---------------------------------------------------------------------------
// Bidirectional Mamba block, MI355X. Round 32:
//  - REVERT R31 deferred-reduction (regression: occupancy 57->26%, 3.7M bank
//    conflicts, +19us). Scans back to R28 form (known-good).
//  - kscanA/kscanC: 2 CHUNKS PER BLOCK (c and c+32, grid 1024->512): each
//    thread runs two independent h/S chains -> stalls of one chain filled by
//    the other (zero added instructions, same total work). kscanC's second
//    seed-fold continues from the first (same sequence, bit-identical, half
//    the fold). LDS 12.8->24.7KB still 6 blocks/CU = 24 waves/CU.
// Shapes: B=4, C=64, D=128, L=4096 (l = h*256 + w*16 + t), N=16, R=8.
// ---------------------------------------------------------------------------

#define NL 4096

typedef unsigned short u16;
typedef unsigned int u32;
typedef __attribute__((ext_vector_type(8))) short bf16x8;
typedef __attribute__((ext_vector_type(4))) float f32x4;

__device__ __forceinline__ float siluf_(float x) {
  return x * __builtin_amdgcn_rcpf(1.f + __expf(-x));
}
__device__ __forceinline__ float softplusf_(float x) {
  return (x > 20.f) ? x : __logf(1.f + __expf(x));
}
__device__ __forceinline__ u16 f2bf(float f) {
  u32 u = __float_as_uint(f);
  u += 0x7fffu + ((u >> 16) & 1u);
  return (u16)(u >> 16);
}

// Sum over the 16-lane DPP row via rotations 1,2,4,8 (VALU pipe, no DS).
__device__ __forceinline__ float rowsum16_(float p) {
  int q;
  q = __builtin_amdgcn_mov_dpp(__float_as_int(p), 0x121, 0xf, 0xf, false);
  p += __int_as_float(q);
  q = __builtin_amdgcn_mov_dpp(__float_as_int(p), 0x122, 0xf, 0xf, false);
  p += __int_as_float(q);
  q = __builtin_amdgcn_mov_dpp(__float_as_int(p), 0x124, 0xf, 0xf, false);
  p += __int_as_float(q);
  q = __builtin_amdgcn_mov_dpp(__float_as_int(p), 0x128, 0xf, 0xf, false);
  p += __int_as_float(q);
  return p;
}

// Per-b slab offsets (fp32 elements)
#define OXZ  0u          // xz [256][4096] fp32
#define OUCF 1048576u    // ucf [128][4096] fp32
#define OUCB 1572864u    // ucb [128][4096] fp32 (flipped coords)
#define ODLF 2424832u    // dlf [128][4096] fp32
#define ODLB 2949120u    // dlb [128][4096] fp32 (flipped coords)
#define OYF  3473408u    // yf [128][4096] fp32
#define OYB  3997696u    // yb [128][4096] fp32 (flipped coords)
#define OO   4521984u    // scan scratch: P [262144] S [262144] fp32
#define OO2  5046272u    // bct bf16 until kscanC; then o2 [4096][64] fp32
#define PER_B 5570560u
// Wbf8 [8 xcd][27][64][64] bf16 lives at ws + bcnt*PER_B

#define NCH 64   // scan chunks
#define CL  64   // chunk length
#define WB1 110592u  // u16 elems per Wbf copy (27*64*64)

// 1. xz[e,l] = sum_c in_proj_w[e,c] * seq[c,l].
__global__ __launch_bounds__(256) void kxz(
    const float* __restrict__ x, const float* __restrict__ wip,
    float* __restrict__ ws, int b0) {
  int bi = blockIdx.y, gb = b0 + bi;
  float* s = ws + (size_t)bi * PER_B;
  int bid = blockIdx.x;
  int h = bid >> 4, w = bid & 15;
  int tid = threadIdx.x;
  __shared__ float xs[64][16];
  for (int i = tid; i < 1024; i += 256) {
    int c = i >> 4, t = i & 15;
    xs[c][t] = x[(size_t)(gb * 64 + c) * NL + t * 256 + h * 16 + w];
  }
  __syncthreads();
  int e = tid;
  float acc[16];
#pragma unroll
  for (int t = 0; t < 16; ++t) acc[t] = 0.f;
  for (int c = 0; c < 64; ++c) {
    float wv = wip[e * 64 + c];
#pragma unroll
    for (int t = 0; t < 16; ++t) acc[t] = fmaf(wv, xs[c][t], acc[t]);
  }
  float4* dst = (float4*)(s + OXZ + (size_t)e * NL + h * 256 + w * 16);
#pragma unroll
  for (int q = 0; q < 4; ++q)
    dst[q] = make_float4(acc[q * 4], acc[q * 4 + 1], acc[q * 4 + 2], acc[q * 4 + 3]);
}

// 2. Fused prep per (bi, dir, 32-l tile): dwconv+silu, x_dbl via MFMA, delta,
// bct. Grid x = 256 (lt 128 x dir 2). uc/dl stored fp32.
__global__ __launch_bounds__(256) void k2prep(
    const float* __restrict__ cwf, const float* __restrict__ cbf,
    const float* __restrict__ xpf, const float* __restrict__ dtwf,
    const float* __restrict__ dtbf,
    const float* __restrict__ cwb, const float* __restrict__ cbb,
    const float* __restrict__ xpb, const float* __restrict__ dtwb,
    const float* __restrict__ dtbb,
    float* __restrict__ ws) {
  int bi = blockIdx.y;
  float* s = ws + (size_t)bi * PER_B;
  int bx = blockIdx.x;
  int lt = bx >> 1, dir = bx & 1;
  int l0 = lt * 32;
  int lout0 = dir ? (127 - lt) * 32 : l0;   // output base (flipped for bwd)
  int tid = threadIdx.x;

  __shared__ float pool[128 * 40];   // X[128][40] during dwconv; xds after
  __shared__ u16 uct[32][136];       // uc transposed bf16 (d-contig, 16B rows)
  float (*X)[40] = (float(*)[40])pool;

  for (int i = tid; i < 128 * 38; i += 256) {
    int d = i / 38, j = i - d * 38;
    int l = l0 - 3 + j;
    X[d][j] = (l >= 0 && l < NL) ? s[OXZ + (size_t)d * NL + l] : 0.f;
  }
  __syncthreads();

  const float* cw = dir ? cwb : cwf;
  const float* cb = dir ? cbb : cbf;
  float* ucg = s + (dir ? OUCB : OUCF);
  for (int i = tid; i < 128 * 32; i += 256) {
    int d = i >> 5, li = i & 31;
    float a = cb[d];
    if (dir == 0) {
#pragma unroll
      for (int k = 0; k < 4; ++k) a = fmaf(cw[d * 4 + k], X[d][li + k], a);
    } else {
#pragma unroll
      for (int k = 0; k < 4; ++k) a = fmaf(cw[d * 4 + k], X[d][37 - li - k], a);
    }
    a = siluf_(a);
    uct[li][d] = f2bf(a);
    ucg[(size_t)d * NL + lout0 + li] = a;
  }
  __syncthreads();  // X dead; pool becomes xds [40][33]

  // x_dbl via MFMA 16x16x32: D[e 48][l 32], K=128. Units (et,lt2) = 6 over
  // 4 waves (waves 0,1 take two units).
  float* xds = pool;
  {
    int wid = tid >> 6, lane = tid & 63;
    int n16 = lane & 15, kg = lane >> 4;
    const float* xp = dir ? xpb : xpf;
#pragma unroll
    for (int rep = 0; rep < 2; ++rep) {
      int id = wid + rep * 4;
      if (id < 6) {
        int et = id >> 1, lt2 = id & 1;
        f32x4 acc = {};
#pragma unroll
        for (int ks = 0; ks < 4; ++ks) {
          bf16x8 bfrag = *(const bf16x8*)&uct[lt2 * 16 + n16][ks * 32 + kg * 8];
          int e = et * 16 + n16;
          int ec = (e < 40) ? e : 39;        // clamp addr; rows >=40 discarded
          const float* pa = xp + ec * 128 + ks * 32 + kg * 8;
          float4 a0 = *(const float4*)pa;
          float4 a1 = *(const float4*)(pa + 4);
          bf16x8 af;
          af[0] = (short)f2bf(a0.x); af[1] = (short)f2bf(a0.y);
          af[2] = (short)f2bf(a0.z); af[3] = (short)f2bf(a0.w);
          af[4] = (short)f2bf(a1.x); af[5] = (short)f2bf(a1.y);
          af[6] = (short)f2bf(a1.z); af[7] = (short)f2bf(a1.w);
          acc = __builtin_amdgcn_mfma_f32_16x16x32_bf16(af, bfrag, acc, 0, 0, 0);
        }
        // D layout: col = lane&15 (l), row = kg*4 + rg (e within 16-tile)
#pragma unroll
        for (int rg = 0; rg < 4; ++rg) {
          int e = et * 16 + kg * 4 + rg;
          if (e < 40) xds[e * 33 + lt2 * 16 + n16] = acc[rg];
        }
      }
    }
  }
  __syncthreads();

  const float* dtw = dir ? dtwb : dtwf;
  const float* dtb = dir ? dtbb : dtbf;
  float* dlg = s + (dir ? ODLB : ODLF);
  for (int i = tid; i < 128 * 32; i += 256) {
    int d = i >> 5, li = i & 31;
    float pre = dtb[d];
#pragma unroll
    for (int r = 0; r < 8; ++r)
      pre = fmaf(dtw[d * 8 + r], xds[r * 33 + li], pre);
    dlg[(size_t)d * NL + lout0 + li] = softplusf_(pre);
  }
  u16* bctp = (u16*)(s + OO2);
  for (int i = tid; i < 32 * 32; i += 256) {
    int li = i >> 5, k = i & 31;
    bctp[((size_t)dir * 4096 + lout0 + li) * 32 + k] = f2bf(xds[(8 + k) * 33 + li]);
  }
}

// 5a. Phase A: 16 d-rows/block, TWO chunks (c, c+32) per block; B-half of
// bct staged to fp32 LDS; fp32 dl/uc float4 loads; fully unrolled.
__global__ __launch_bounds__(256) void kscanA(
    const float* __restrict__ Alf, const float* __restrict__ Alb,
    float* __restrict__ ws) {
  int bi = blockIdx.y;
  float* s = ws + (size_t)bi * PER_B;
  int xid = blockIdx.x;
  int c0 = xid >> 4, dir = (xid >> 3) & 1, d8 = xid & 7;
  int c1 = c0 + 32;
  int tid = threadIdx.x;
  int wv = tid >> 6, lane = tid & 63;
  int n = lane & 15, g = lane >> 4;
  int d = d8 * 16 + wv * 4 + g;
  int l0a = c0 * CL, l0b = c1 * CL;
  __shared__ float bl[2][CL * 16];
  {
    const u16* bctp = (const u16*)(s + OO2);
    for (int i = tid; i < 2 * CL * 16; i += 256) {
      int which = i >> 10, r = i & 1023;
      int l = r >> 4, k = r & 15;
      size_t lg = (size_t)dir * 4096 + (which ? l0b : l0a) + l;
      bl[which][r] = __uint_as_float(((u32)bctp[lg * 32 + k]) << 16);
    }
  }
  __syncthreads();
  const float* ucpA = s + (dir ? OUCB : OUCF) + (size_t)d * NL + l0a;
  const float* dlpA = s + (dir ? ODLB : ODLF) + (size_t)d * NL + l0a;
  const float* ucpB = s + (dir ? OUCB : OUCF) + (size_t)d * NL + l0b;
  const float* dlpB = s + (dir ? ODLB : ODLF) + (size_t)d * NL + l0b;
  const float* blA = bl[0] + n;
  const float* blBp = bl[1] + n;
  float A = -__expf((dir ? Alb : Alf)[d * 16 + n]);
  float P0 = 1.f, S0 = 0.f, P1 = 1.f, S1 = 0.f;
#pragma unroll
  for (int i0 = 0; i0 < CL; i0 += 8) {
    float4 da0 = *(const float4*)(dlpA + i0);
    float4 da1 = *(const float4*)(dlpA + i0 + 4);
    float4 ua0 = *(const float4*)(ucpA + i0);
    float4 ua1 = *(const float4*)(ucpA + i0 + 4);
    float4 db0 = *(const float4*)(dlpB + i0);
    float4 db1 = *(const float4*)(dlpB + i0 + 4);
    float4 ub0 = *(const float4*)(ucpB + i0);
    float4 ub1 = *(const float4*)(ucpB + i0 + 4);
    float dvA[8] = {da0.x, da0.y, da0.z, da0.w, da1.x, da1.y, da1.z, da1.w};
    float uvA[8] = {ua0.x, ua0.y, ua0.z, ua0.w, ua1.x, ua1.y, ua1.z, ua1.w};
    float dvB[8] = {db0.x, db0.y, db0.z, db0.w, db1.x, db1.y, db1.z, db1.w};
    float uvB[8] = {ub0.x, ub0.y, ub0.z, ub0.w, ub1.x, ub1.y, ub1.z, ub1.w};
#pragma unroll
    for (int j = 0; j < 8; ++j) {
      float dA0 = __expf(dvA[j] * A);
      S0 = fmaf(dA0, S0, dvA[j] * blA[(i0 + j) * 16] * uvA[j]);
      P0 *= dA0;
      float dA1 = __expf(dvB[j] * A);
      S1 = fmaf(dA1, S1, dvB[j] * blBp[(i0 + j) * 16] * uvB[j]);
      P1 *= dA1;
    }
  }
  size_t cidx0 = ((size_t)(c0 * 2 + dir) * 128 + d) * 16 + n;
  size_t cidx1 = ((size_t)(c1 * 2 + dir) * 128 + d) * 16 + n;
  s[OO + cidx0] = P0;
  s[OO + 262144u + cidx0] = S0;
  s[OO + cidx1] = P1;
  s[OO + 262144u + cidx1] = S1;
}

// 5c. Phase C: self-seeded re-scan, TWO chunks (c, c+32) per block; second
// seed continues the first fold (same sequence, bit-identical); fp32 dl/uc;
// DPP row-sum; ps writes batched per 8 steps.
__global__ __launch_bounds__(256) void kscanC(
    const float* __restrict__ Alf, const float* __restrict__ Df,
    const float* __restrict__ Alb, const float* __restrict__ Db,
    float* __restrict__ ws) {
  int bi = blockIdx.y;
  float* s = ws + (size_t)bi * PER_B;
  int xid = blockIdx.x;
  int c0 = xid >> 4, dir = (xid >> 3) & 1, d8 = xid & 7;
  int c1 = c0 + 32;
  int tid = threadIdx.x;
  int wv = tid >> 6, lane = tid & 63;
  int n = lane & 15, g = lane >> 4;
  int d = d8 * 16 + wv * 4 + g;
  int l0a = c0 * CL, l0b = c1 * CL;
  __shared__ float bl[2][CL * 32];
  __shared__ float ps[2][16][65];
  {
    const u16* bctp = (const u16*)(s + OO2);
    for (int i = tid; i < 2 * CL * 32; i += 256) {
      int which = i >> 11, r = i & 2047;
      size_t lg = (size_t)dir * 4096 + (which ? l0b : l0a);
      bl[which][r] = __uint_as_float(((u32)bctp[lg * 32 + r]) << 16);
    }
  }
  // Self-seed: fold chunks < c0 -> h0; continue c0..c1-1 -> h1.
  float h0 = 0.f, h1;
  {
    size_t stepi = (size_t)d * 16 + n;
    float h = 0.f;
#pragma unroll 4
    for (int c = 0; c < c0; ++c) {
      size_t idx = ((size_t)(c * 2 + dir) * 128) * 16 + stepi;
      h = fmaf(s[OO + idx], h, s[OO + 262144u + idx]);
    }
    h0 = h;
#pragma unroll 4
    for (int c = c0; c < c1; ++c) {
      size_t idx = ((size_t)(c * 2 + dir) * 128) * 16 + stepi;
      h = fmaf(s[OO + idx], h, s[OO + 262144u + idx]);
    }
    h1 = h;
  }
  __syncthreads();
  const float* ucpA = s + (dir ? OUCB : OUCF) + (size_t)d * NL + l0a;
  const float* dlpA = s + (dir ? ODLB : ODLF) + (size_t)d * NL + l0a;
  const float* ucpB = s + (dir ? OUCB : OUCF) + (size_t)d * NL + l0b;
  const float* dlpB = s + (dir ? ODLB : ODLF) + (size_t)d * NL + l0b;
  const float* blA = bl[0] + n;
  const float* blBp = bl[1] + n;
  float* ybase = s + (dir ? OYB : OYF);
  float A = -__expf((dir ? Alb : Alf)[d * 16 + n]);
  float Dv = (dir ? Db : Df)[d];
  int prow = wv * 4 + g;
#pragma unroll
  for (int i0 = 0; i0 < CL; i0 += 8) {
    float4 da0 = *(const float4*)(dlpA + i0);
    float4 da1 = *(const float4*)(dlpA + i0 + 4);
    float4 ua0 = *(const float4*)(ucpA + i0);
    float4 ua1 = *(const float4*)(ucpA + i0 + 4);
    float4 db0 = *(const float4*)(dlpB + i0);
    float4 db1 = *(const float4*)(dlpB + i0 + 4);
    float4 ub0 = *(const float4*)(ucpB + i0);
    float4 ub1 = *(const float4*)(ucpB + i0 + 4);
    float dvA[8] = {da0.x, da0.y, da0.z, da0.w, da1.x, da1.y, da1.z, da1.w};
    float uvA[8] = {ua0.x, ua0.y, ua0.z, ua0.w, ua1.x, ua1.y, ua1.z, ua1.w};
    float dvB[8] = {db0.x, db0.y, db0.z, db0.w, db1.x, db1.y, db1.z, db1.w};
    float uvB[8] = {ub0.x, ub0.y, ub0.z, ub0.w, ub1.x, ub1.y, ub1.z, ub1.w};
    float yv0[8], yv1[8];
#pragma unroll
    for (int j = 0; j < 8; ++j) {
      float dA0 = __expf(dvA[j] * A);
      h0 = fmaf(dA0, h0, dvA[j] * blA[(i0 + j) * 32] * uvA[j]);
      float p0 = rowsum16_(h0 * blA[(i0 + j) * 32 + 16]);
      yv0[j] = fmaf(uvA[j], Dv, p0);
      float dA1 = __expf(dvB[j] * A);
      h1 = fmaf(dA1, h1, dvB[j] * blBp[(i0 + j) * 32] * uvB[j]);
      float p1 = rowsum16_(h1 * blBp[(i0 + j) * 32 + 16]);
      yv1[j] = fmaf(uvB[j], Dv, p1);
    }
    if (n == 0) {
#pragma unroll
      for (int j = 0; j < 8; ++j) {
        ps[0][prow][i0 + j] = yv0[j];
        ps[1][prow][i0 + j] = yv1[j];
      }
    }
  }
  __syncthreads();
  for (int i = tid; i < 2 * 16 * CL; i += 256) {
    int which = i >> 10;
    int r = i & 1023;
    int row = r >> 6, col = r & 63;
    ybase[(size_t)(d8 * 16 + row) * NL + (which ? l0b : l0a) + col] =
        ps[which][row][col];
  }
}

// 6. Fused gate + out-proj via MFMA. Block = 32-l tile.
__global__ __launch_bounds__(256) void koutg(
    const float* __restrict__ wout, float* __restrict__ ws) {
  int bi = blockIdx.y;
  float* s = ws + (size_t)bi * PER_B;
  int lt = blockIdx.x;
  int l0 = lt * 32;
  int tid = threadIdx.x;
  __shared__ u16 otb[32][136];
  for (int i = tid; i < 128 * 32; i += 256) {
    int d = i >> 5, li = i & 31;
    int l = l0 + li;
    float z = s[OXZ + (size_t)(128 + d) * NL + l];
    float v = s[OYF + (size_t)d * NL + l] + s[OYB + (size_t)d * NL + (NL - 1 - l)];
    otb[li][d] = f2bf(v * siluf_(z));
  }
  __syncthreads();
  int wid = tid >> 6, lane = tid & 63;
  int n16 = lane & 15, kg = lane >> 4;
  f32x4 acc[2] = {};   // [l2 tile]
  const float* wr = wout + (size_t)(wid * 16 + n16) * 128 + kg * 8;
#pragma unroll
  for (int ks = 0; ks < 4; ++ks) {
    const float* pa = wr + ks * 32;
    float4 a0 = *(const float4*)pa;
    float4 a1 = *(const float4*)(pa + 4);
    bf16x8 af;
    af[0] = (short)f2bf(a0.x); af[1] = (short)f2bf(a0.y);
    af[2] = (short)f2bf(a0.z); af[3] = (short)f2bf(a0.w);
    af[4] = (short)f2bf(a1.x); af[5] = (short)f2bf(a1.y);
    af[6] = (short)f2bf(a1.z); af[7] = (short)f2bf(a1.w);
    bf16x8 b0 = *(const bf16x8*)&otb[n16][ks * 32 + kg * 8];
    bf16x8 b1 = *(const bf16x8*)&otb[16 + n16][ks * 32 + kg * 8];
    acc[0] = __builtin_amdgcn_mfma_f32_16x16x32_bf16(af, b0, acc[0], 0, 0, 0);
    acc[1] = __builtin_amdgcn_mfma_f32_16x16x32_bf16(af, b1, acc[1], 0, 0, 0);
  }
  // D: col = lane&15 (l), row = kg*4+rg (c in 16-tile); rg = consecutive c.
#pragma unroll
  for (int l2 = 0; l2 < 2; ++l2) {
    float4 st = make_float4(acc[l2][0], acc[l2][1], acc[l2][2], acc[l2][3]);
    *(float4*)&s[OO2 + (size_t)(l0 + l2 * 16 + n16) * 64 + wid * 16 + kg * 4] = st;
  }
}

// 6.5. Weight prep: Wbf8[xcd 8][27][co 64][ci 64] bf16 at ws + bcnt*PER_B.
__global__ __launch_bounds__(256) void kprepw(
    const float* __restrict__ pw, float* __restrict__ wdst) {
  int off = blockIdx.x;
  u16* wb = (u16*)wdst;
  int tid = threadIdx.x;
  for (int i = tid; i < 4096; i += 256) {
    int co = i >> 6, ci = i & 63;
    u16 v = f2bf(pw[(size_t)(co * 64 + ci) * 27 + off]);
#pragma unroll
    for (int xc = 0; xc < 8; ++xc)
      wb[(size_t)xc * WB1 + off * 4096 + i] = v;
  }
}

// 7. conv3d (bf16 implicit GEMM on MFMA) + FUSED 1x1x1 norm mix. (R27 form.)
__global__ __launch_bounds__(256, 2) void kconv3(
    const float* __restrict__ pb, const float* __restrict__ nw,
    const float* __restrict__ nb, const float* __restrict__ xin,
    float* __restrict__ out, const u16* __restrict__ wb,
    float* __restrict__ ws, int b0) {
  int bi = blockIdx.y, gb = b0 + bi;
  float* s = ws + (size_t)bi * PER_B;
  int bx = blockIdx.x;
  int t = bx >> 3, hq = bx & 7;
  int h0 = hq * 2;
  int tid = threadIdx.x;
  const float* xr = s + OO2;              // o2 in c-major reshape view

  __shared__ u16 Xs[3 * 4 * 18 * 72];     // 31104 B; later aliased as cx
  float* cx = (float*)Xs;                 // cx[64][33] = 8448 B
  {
    u32* xz32 = (u32*)Xs;
    for (int i = tid; i < 3 * 4 * 18 * 72 / 2; i += 256) xz32[i] = 0u;
  }
  __syncthreads();
  {
    int ci = tid >> 2, wq = tid & 3;
#pragma unroll
    for (int rowc = 0; rowc < 12; ++rowc) {
      int tt = rowc >> 2, hh = rowc & 3;
      int ts = t + tt - 1, hs = h0 + hh - 1;
      if (ts < 0 || ts > 15 || hs < 0 || hs > 15) continue;
      float4 v = *(const float4*)(xr + (size_t)ci * NL + ts * 256 + hs * 16 + wq * 4);
      int rb = (tt * 4 + hh) * 18 + 1 + wq * 4;
      Xs[(rb + 0) * 72 + ci] = f2bf(v.x);
      Xs[(rb + 1) * 72 + ci] = f2bf(v.y);
      Xs[(rb + 2) * 72 + ci] = f2bf(v.z);
      Xs[(rb + 3) * 72 + ci] = f2bf(v.w);
    }
  }
  __syncthreads();

  int wid = tid >> 6, lane = tid & 63;
  int cq = wid;
  int n16 = lane & 15, kg = lane >> 4;
  f32x4 acc[2] = {};

  const u16* wbA = wb + (size_t)(bx & 7) * WB1 +
                   (size_t)(cq * 16 + n16) * 64 + kg * 8;
#pragma unroll
  for (int kt = 0; kt < 3; ++kt)
#pragma unroll
    for (int kh = 0; kh < 3; ++kh) {
#pragma unroll
      for (int kw = 0; kw < 3; ++kw) {
        int off = (kt * 3 + kh) * 3 + kw;
        const u16* pa = wbA + off * 4096;
#pragma unroll
        for (int st = 0; st < 2; ++st) {
          int kb = st * 32;
          bf16x8 a0 = *(const bf16x8*)(pa + kb);
#pragma unroll
          for (int l2 = 0; l2 < 2; ++l2) {
            int r = (kt * 4 + l2 + kh) * 18 + n16 + kw;
            bf16x8 b0 = *(const bf16x8*)(&Xs[r * 72 + kb + kg * 8]);
            acc[l2] = __builtin_amdgcn_mfma_f32_16x16x32_bf16(a0, b0, acc[l2], 0, 0, 0);
          }
        }
      }
    }
  __syncthreads();

#pragma unroll
  for (int l2 = 0; l2 < 2; ++l2) {
    int lp = l2 * 16 + n16;
    int lg = t * 256 + (h0 + l2) * 16 + n16;
#pragma unroll
    for (int rg = 0; rg < 4; ++rg) {
      int co = cq * 16 + kg * 4 + rg;
      cx[co * 33 + lp] = acc[l2][rg] + pb[co] +
                         xin[(size_t)(gb * 64 + co) * NL + lg];
    }
  }
  __syncthreads();

  {
    int co2 = tid >> 2, pq = tid & 3;
    float mac[8];
#pragma unroll
    for (int j = 0; j < 8; ++j) mac[j] = 0.f;
    for (int ci = 0; ci < 64; ci += 4) {
      float4 w4 = *(const float4*)&nw[co2 * 64 + ci];
      float wv[4] = {w4.x, w4.y, w4.z, w4.w};
#pragma unroll
      for (int cc = 0; cc < 4; ++cc) {
        const float* row = &cx[(ci + cc) * 33 + pq * 8];
        float4 a = *(const float4*)&row[0];
        float4 b = *(const float4*)&row[4];
        mac[0] = fmaf(wv[cc], a.x, mac[0]);  mac[1] = fmaf(wv[cc], a.y, mac[1]);
        mac[2] = fmaf(wv[cc], a.z, mac[2]);  mac[3] = fmaf(wv[cc], a.w, mac[3]);
        mac[4] = fmaf(wv[cc], b.x, mac[4]);  mac[5] = fmaf(wv[cc], b.y, mac[5]);
        mac[6] = fmaf(wv[cc], b.z, mac[6]);  mac[7] = fmaf(wv[cc], b.w, mac[7]);
      }
    }
    float bias = nb[co2];
    float4* dst = (float4*)(out + (size_t)(gb * 64 + co2) * NL +
                            t * 256 + h0 * 16 + pq * 8);
    dst[0] = make_float4(mac[0] + bias, mac[1] + bias, mac[2] + bias, mac[3] + bias);
    dst[1] = make_float4(mac[4] + bias, mac[5] + bias, mac[6] + bias, mac[7] + bias);
  }
}

// ---------------------------------------------------------------------------
extern "C" void kernel_launch(void* const* d_in, const int* in_sizes, int n_in,
                              void* d_out, int out_size, void* d_ws, size_t ws_size,
                              hipStream_t stream) {
  const float* x    = (const float*)d_in[0];
  const float* wip  = (const float*)d_in[1];
  const float* cwf  = (const float*)d_in[2];
  const float* cbf  = (const float*)d_in[3];
  const float* xpf  = (const float*)d_in[4];
  const float* dtwf = (const float*)d_in[5];
  const float* dtbf = (const float*)d_in[6];
  const float* Alf  = (const float*)d_in[7];
  const float* Df   = (const float*)d_in[8];
  const float* cwb  = (const float*)d_in[9];
  const float* cbb  = (const float*)d_in[10];
  const float* xpb  = (const float*)d_in[11];
  const float* dtwb = (const float*)d_in[12];
  const float* dtbb = (const float*)d_in[13];
  const float* Alb  = (const float*)d_in[14];
  const float* Db   = (const float*)d_in[15];
  const float* wout = (const float*)d_in[16];
  const float* pw   = (const float*)d_in[17];
  const float* pb   = (const float*)d_in[18];
  const float* nw   = (const float*)d_in[19];
  const float* nb   = (const float*)d_in[20];

  const size_t PER_B_BYTES = (size_t)PER_B * 4;  // 22,282,240 per batch slab
  const size_t WB_BYTES = 8u * WB1 * 2u;         // 1,769,472 (8 Wbf replicas)
  int bcnt;
  if (ws_size >= 4 * PER_B_BYTES + WB_BYTES) bcnt = 4;
  else if (ws_size >= PER_B_BYTES + WB_BYTES) bcnt = 1;
  else return;
  int passes = 4 / bcnt;

  float* ws = (float*)d_ws;
  float* wsW = ws + (size_t)bcnt * PER_B;
  kprepw<<<dim3(27), 256, 0, stream>>>(pw, wsW);
  for (int p = 0; p < passes; ++p) {
    int b0 = p * bcnt;
    kxz   <<<dim3(256, bcnt), 256, 0, stream>>>(x, wip, ws, b0);
    k2prep<<<dim3(256, bcnt), 256, 0, stream>>>(cwf, cbf, xpf, dtwf, dtbf,
                                                cwb, cbb, xpb, dtwb, dtbb, ws);
    kscanA<<<dim3(512, bcnt), 256, 0, stream>>>(Alf, Alb, ws);
    kscanC<<<dim3(512, bcnt), 256, 0, stream>>>(Alf, Df, Alb, Db, ws);
    koutg <<<dim3(128, bcnt), 256, 0, stream>>>(wout, ws);
    kconv3<<<dim3(128, bcnt), 256, 0, stream>>>(pb, nw, nb, x, (float*)d_out,
                                                (const u16*)wsW, ws, b0);
  }
}

// Round 13
// 257.766 us; speedup vs baseline: 1.0690x; 1.0116x over previous
//
#include <hip/hip_runtime.h>

// ---------------------------------------------------------------------------
// Bidirectional Mamba block, MI355X. Round 33:
//  - RESTORE R28 scan kernels (empirical best: 257.84us total). R29-R32's
//    five kscanC variants (reorder / ring-prefetch / deferred-reduce /
//    2-chunk-ILP) all measured neutral or regressions; kscanC's ~47us is the
//    practical floor of the two-pass chunked scan (VALU 62-67%, HBM 12%).
//  - kscanA: P via exp(A*sum(dv)) (serial mul chain -> add; verified safe
//    in R31, absmax unchanged).
//  - Keeps all verified wins: MFMA conv3/x_dbl/outproj, knorm fusion,
//    XCD-local weight replicas, fp32 scan streams, kscanB elimination.
// Shapes: B=4, C=64, D=128, L=4096 (l = h*256 + w*16 + t), N=16, R=8.
// ---------------------------------------------------------------------------

#define NL 4096

typedef unsigned short u16;
typedef unsigned int u32;
typedef __attribute__((ext_vector_type(8))) short bf16x8;
typedef __attribute__((ext_vector_type(4))) float f32x4;

__device__ __forceinline__ float siluf_(float x) {
  return x * __builtin_amdgcn_rcpf(1.f + __expf(-x));
}
__device__ __forceinline__ float softplusf_(float x) {
  return (x > 20.f) ? x : __logf(1.f + __expf(x));
}
__device__ __forceinline__ u16 f2bf(float f) {
  u32 u = __float_as_uint(f);
  u += 0x7fffu + ((u >> 16) & 1u);
  return (u16)(u >> 16);
}

// Sum over the 16-lane DPP row via rotations 1,2,4,8 (VALU pipe, no DS).
__device__ __forceinline__ float rowsum16_(float p) {
  int q;
  q = __builtin_amdgcn_mov_dpp(__float_as_int(p), 0x121, 0xf, 0xf, false);
  p += __int_as_float(q);
  q = __builtin_amdgcn_mov_dpp(__float_as_int(p), 0x122, 0xf, 0xf, false);
  p += __int_as_float(q);
  q = __builtin_amdgcn_mov_dpp(__float_as_int(p), 0x124, 0xf, 0xf, false);
  p += __int_as_float(q);
  q = __builtin_amdgcn_mov_dpp(__float_as_int(p), 0x128, 0xf, 0xf, false);
  p += __int_as_float(q);
  return p;
}

// Per-b slab offsets (fp32 elements)
#define OXZ  0u          // xz [256][4096] fp32
#define OUCF 1048576u    // ucf [128][4096] fp32
#define OUCB 1572864u    // ucb [128][4096] fp32 (flipped coords)
#define ODLF 2424832u    // dlf [128][4096] fp32
#define ODLB 2949120u    // dlb [128][4096] fp32 (flipped coords)
#define OYF  3473408u    // yf [128][4096] fp32
#define OYB  3997696u    // yb [128][4096] fp32 (flipped coords)
#define OO   4521984u    // scan scratch: P [262144] S [262144] fp32
#define OO2  5046272u    // bct bf16 until kscanC; then o2 [4096][64] fp32
#define PER_B 5570560u
// Wbf8 [8 xcd][27][64][64] bf16 lives at ws + bcnt*PER_B

#define NCH 64   // scan chunks
#define CL  64   // chunk length
#define WB1 110592u  // u16 elems per Wbf copy (27*64*64)

// 1. xz[e,l] = sum_c in_proj_w[e,c] * seq[c,l].
__global__ __launch_bounds__(256) void kxz(
    const float* __restrict__ x, const float* __restrict__ wip,
    float* __restrict__ ws, int b0) {
  int bi = blockIdx.y, gb = b0 + bi;
  float* s = ws + (size_t)bi * PER_B;
  int bid = blockIdx.x;
  int h = bid >> 4, w = bid & 15;
  int tid = threadIdx.x;
  __shared__ float xs[64][16];
  for (int i = tid; i < 1024; i += 256) {
    int c = i >> 4, t = i & 15;
    xs[c][t] = x[(size_t)(gb * 64 + c) * NL + t * 256 + h * 16 + w];
  }
  __syncthreads();
  int e = tid;
  float acc[16];
#pragma unroll
  for (int t = 0; t < 16; ++t) acc[t] = 0.f;
  for (int c = 0; c < 64; ++c) {
    float wv = wip[e * 64 + c];
#pragma unroll
    for (int t = 0; t < 16; ++t) acc[t] = fmaf(wv, xs[c][t], acc[t]);
  }
  float4* dst = (float4*)(s + OXZ + (size_t)e * NL + h * 256 + w * 16);
#pragma unroll
  for (int q = 0; q < 4; ++q)
    dst[q] = make_float4(acc[q * 4], acc[q * 4 + 1], acc[q * 4 + 2], acc[q * 4 + 3]);
}

// 2. Fused prep per (bi, dir, 32-l tile): dwconv+silu, x_dbl via MFMA, delta,
// bct. Grid x = 256 (lt 128 x dir 2). uc/dl stored fp32.
__global__ __launch_bounds__(256) void k2prep(
    const float* __restrict__ cwf, const float* __restrict__ cbf,
    const float* __restrict__ xpf, const float* __restrict__ dtwf,
    const float* __restrict__ dtbf,
    const float* __restrict__ cwb, const float* __restrict__ cbb,
    const float* __restrict__ xpb, const float* __restrict__ dtwb,
    const float* __restrict__ dtbb,
    float* __restrict__ ws) {
  int bi = blockIdx.y;
  float* s = ws + (size_t)bi * PER_B;
  int bx = blockIdx.x;
  int lt = bx >> 1, dir = bx & 1;
  int l0 = lt * 32;
  int lout0 = dir ? (127 - lt) * 32 : l0;   // output base (flipped for bwd)
  int tid = threadIdx.x;

  __shared__ float pool[128 * 40];   // X[128][40] during dwconv; xds after
  __shared__ u16 uct[32][136];       // uc transposed bf16 (d-contig, 16B rows)
  float (*X)[40] = (float(*)[40])pool;

  for (int i = tid; i < 128 * 38; i += 256) {
    int d = i / 38, j = i - d * 38;
    int l = l0 - 3 + j;
    X[d][j] = (l >= 0 && l < NL) ? s[OXZ + (size_t)d * NL + l] : 0.f;
  }
  __syncthreads();

  const float* cw = dir ? cwb : cwf;
  const float* cb = dir ? cbb : cbf;
  float* ucg = s + (dir ? OUCB : OUCF);
  for (int i = tid; i < 128 * 32; i += 256) {
    int d = i >> 5, li = i & 31;
    float a = cb[d];
    if (dir == 0) {
#pragma unroll
      for (int k = 0; k < 4; ++k) a = fmaf(cw[d * 4 + k], X[d][li + k], a);
    } else {
#pragma unroll
      for (int k = 0; k < 4; ++k) a = fmaf(cw[d * 4 + k], X[d][37 - li - k], a);
    }
    a = siluf_(a);
    uct[li][d] = f2bf(a);
    ucg[(size_t)d * NL + lout0 + li] = a;
  }
  __syncthreads();  // X dead; pool becomes xds [40][33]

  // x_dbl via MFMA 16x16x32: D[e 48][l 32], K=128. Units (et,lt2) = 6 over
  // 4 waves (waves 0,1 take two units).
  float* xds = pool;
  {
    int wid = tid >> 6, lane = tid & 63;
    int n16 = lane & 15, kg = lane >> 4;
    const float* xp = dir ? xpb : xpf;
#pragma unroll
    for (int rep = 0; rep < 2; ++rep) {
      int id = wid + rep * 4;
      if (id < 6) {
        int et = id >> 1, lt2 = id & 1;
        f32x4 acc = {};
#pragma unroll
        for (int ks = 0; ks < 4; ++ks) {
          bf16x8 bfrag = *(const bf16x8*)&uct[lt2 * 16 + n16][ks * 32 + kg * 8];
          int e = et * 16 + n16;
          int ec = (e < 40) ? e : 39;        // clamp addr; rows >=40 discarded
          const float* pa = xp + ec * 128 + ks * 32 + kg * 8;
          float4 a0 = *(const float4*)pa;
          float4 a1 = *(const float4*)(pa + 4);
          bf16x8 af;
          af[0] = (short)f2bf(a0.x); af[1] = (short)f2bf(a0.y);
          af[2] = (short)f2bf(a0.z); af[3] = (short)f2bf(a0.w);
          af[4] = (short)f2bf(a1.x); af[5] = (short)f2bf(a1.y);
          af[6] = (short)f2bf(a1.z); af[7] = (short)f2bf(a1.w);
          acc = __builtin_amdgcn_mfma_f32_16x16x32_bf16(af, bfrag, acc, 0, 0, 0);
        }
        // D layout: col = lane&15 (l), row = kg*4 + rg (e within 16-tile)
#pragma unroll
        for (int rg = 0; rg < 4; ++rg) {
          int e = et * 16 + kg * 4 + rg;
          if (e < 40) xds[e * 33 + lt2 * 16 + n16] = acc[rg];
        }
      }
    }
  }
  __syncthreads();

  const float* dtw = dir ? dtwb : dtwf;
  const float* dtb = dir ? dtbb : dtbf;
  float* dlg = s + (dir ? ODLB : ODLF);
  for (int i = tid; i < 128 * 32; i += 256) {
    int d = i >> 5, li = i & 31;
    float pre = dtb[d];
#pragma unroll
    for (int r = 0; r < 8; ++r)
      pre = fmaf(dtw[d * 8 + r], xds[r * 33 + li], pre);
    dlg[(size_t)d * NL + lout0 + li] = softplusf_(pre);
  }
  u16* bctp = (u16*)(s + OO2);
  for (int i = tid; i < 32 * 32; i += 256) {
    int li = i >> 5, k = i & 31;
    bctp[((size_t)dir * 4096 + lout0 + li) * 32 + k] = f2bf(xds[(8 + k) * 33 + li]);
  }
}

// 5a. Phase A: 16 d-rows/block; B-half of chunk bct staged to fp32 LDS;
// fp32 dl/uc float4 loads; fully unrolled; P = exp(A*sum(dv)).
__global__ __launch_bounds__(256) void kscanA(
    const float* __restrict__ Alf, const float* __restrict__ Alb,
    float* __restrict__ ws) {
  int bi = blockIdx.y;
  float* s = ws + (size_t)bi * PER_B;
  int xid = blockIdx.x;
  int chunk = xid >> 4, dir = (xid >> 3) & 1, d8 = xid & 7;
  int tid = threadIdx.x;
  int wv = tid >> 6, lane = tid & 63;
  int n = lane & 15, g = lane >> 4;
  int d = d8 * 16 + wv * 4 + g;
  int l0 = chunk * CL;
  __shared__ float bl[CL * 16];
  {
    const u16* bctp = (const u16*)(s + OO2) + ((size_t)dir * 4096 + l0) * 32;
    for (int i = tid; i < CL * 16; i += 256) {
      int l = i >> 4, k = i & 15;
      bl[i] = __uint_as_float(((u32)bctp[l * 32 + k]) << 16);
    }
  }
  __syncthreads();
  const float* ucp = s + (dir ? OUCB : OUCF) + (size_t)d * NL + l0;
  const float* dlp = s + (dir ? ODLB : ODLF) + (size_t)d * NL + l0;
  const float* blB = bl + n;
  float A = -__expf((dir ? Alb : Alf)[d * 16 + n]);
  float sdv = 0.f, S = 0.f;
#pragma unroll
  for (int i0 = 0; i0 < CL; i0 += 8) {
    float4 dq0 = *(const float4*)(dlp + i0);
    float4 dq1 = *(const float4*)(dlp + i0 + 4);
    float4 uq0 = *(const float4*)(ucp + i0);
    float4 uq1 = *(const float4*)(ucp + i0 + 4);
    float dv[8] = {dq0.x, dq0.y, dq0.z, dq0.w, dq1.x, dq1.y, dq1.z, dq1.w};
    float uv[8] = {uq0.x, uq0.y, uq0.z, uq0.w, uq1.x, uq1.y, uq1.z, uq1.w};
#pragma unroll
    for (int j = 0; j < 8; ++j) {
      float dA = __expf(dv[j] * A);
      S = fmaf(dA, S, dv[j] * blB[(i0 + j) * 16] * uv[j]);
      sdv += dv[j];
    }
  }
  size_t cidx = ((size_t)(chunk * 2 + dir) * 128 + d) * 16 + n;
  s[OO + cidx] = __expf(A * sdv);
  s[OO + 262144u + cidx] = S;
}

// 5c. Phase C: self-seeded re-scan; fp32 dl/uc; fully unrolled; DPP row-sum;
// ps writes batched per 8 steps. (R28 form - empirical best.)
__global__ __launch_bounds__(256) void kscanC(
    const float* __restrict__ Alf, const float* __restrict__ Df,
    const float* __restrict__ Alb, const float* __restrict__ Db,
    float* __restrict__ ws) {
  int bi = blockIdx.y;
  float* s = ws + (size_t)bi * PER_B;
  int xid = blockIdx.x;
  int chunk = xid >> 4, dir = (xid >> 3) & 1, d8 = xid & 7;
  int tid = threadIdx.x;
  int wv = tid >> 6, lane = tid & 63;
  int n = lane & 15, g = lane >> 4;
  int d = d8 * 16 + wv * 4 + g;
  int l0 = chunk * CL;
  __shared__ float bl[CL * 32];
  __shared__ float ps[16][65];
  {
    const u16* bctp = (const u16*)(s + OO2) + ((size_t)dir * 4096 + l0) * 32;
    for (int i = tid; i < CL * 32; i += 256)
      bl[i] = __uint_as_float(((u32)bctp[i]) << 16);
  }
  __syncthreads();
  const float* ucp = s + (dir ? OUCB : OUCF) + (size_t)d * NL + l0;
  const float* dlp = s + (dir ? ODLB : ODLF) + (size_t)d * NL + l0;
  const float* blB = bl + n;
  float* ybase = s + (dir ? OYB : OYF);
  float A = -__expf((dir ? Alb : Alf)[d * 16 + n]);
  float Dv = (dir ? Db : Df)[d];
  // Self-seed: fold P/S of chunks < chunk for this (dir, d, n).
  float h = 0.f;
  {
    size_t stepi = (size_t)d * 16 + n;
#pragma unroll 4
    for (int c = 0; c < chunk; ++c) {
      size_t idx = ((size_t)(c * 2 + dir) * 128) * 16 + stepi;
      float pv = s[OO + idx], sv = s[OO + 262144u + idx];
      h = fmaf(pv, h, sv);
    }
  }
  int prow = wv * 4 + g;
#pragma unroll
  for (int i0 = 0; i0 < CL; i0 += 8) {
    float4 dq0 = *(const float4*)(dlp + i0);
    float4 dq1 = *(const float4*)(dlp + i0 + 4);
    float4 uq0 = *(const float4*)(ucp + i0);
    float4 uq1 = *(const float4*)(ucp + i0 + 4);
    float dv[8] = {dq0.x, dq0.y, dq0.z, dq0.w, dq1.x, dq1.y, dq1.z, dq1.w};
    float uv[8] = {uq0.x, uq0.y, uq0.z, uq0.w, uq1.x, uq1.y, uq1.z, uq1.w};
    float yv[8];
#pragma unroll
    for (int j = 0; j < 8; ++j) {
      float dA = __expf(dv[j] * A);
      h = fmaf(dA, h, dv[j] * blB[(i0 + j) * 32] * uv[j]);
      float p = rowsum16_(h * blB[(i0 + j) * 32 + 16]);
      yv[j] = fmaf(uv[j], Dv, p);
    }
    if (n == 0) {
#pragma unroll
      for (int j = 0; j < 8; ++j) ps[prow][i0 + j] = yv[j];
    }
  }
  __syncthreads();
  for (int i = tid; i < 16 * CL; i += 256) {
    int row = i >> 6, col = i & 63;
    ybase[(size_t)(d8 * 16 + row) * NL + l0 + col] = ps[row][col];
  }
}

// 6. Fused gate + out-proj via MFMA. Block = 32-l tile.
__global__ __launch_bounds__(256) void koutg(
    const float* __restrict__ wout, float* __restrict__ ws) {
  int bi = blockIdx.y;
  float* s = ws + (size_t)bi * PER_B;
  int lt = blockIdx.x;
  int l0 = lt * 32;
  int tid = threadIdx.x;
  __shared__ u16 otb[32][136];
  for (int i = tid; i < 128 * 32; i += 256) {
    int d = i >> 5, li = i & 31;
    int l = l0 + li;
    float z = s[OXZ + (size_t)(128 + d) * NL + l];
    float v = s[OYF + (size_t)d * NL + l] + s[OYB + (size_t)d * NL + (NL - 1 - l)];
    otb[li][d] = f2bf(v * siluf_(z));
  }
  __syncthreads();
  int wid = tid >> 6, lane = tid & 63;
  int n16 = lane & 15, kg = lane >> 4;
  f32x4 acc[2] = {};   // [l2 tile]
  const float* wr = wout + (size_t)(wid * 16 + n16) * 128 + kg * 8;
#pragma unroll
  for (int ks = 0; ks < 4; ++ks) {
    const float* pa = wr + ks * 32;
    float4 a0 = *(const float4*)pa;
    float4 a1 = *(const float4*)(pa + 4);
    bf16x8 af;
    af[0] = (short)f2bf(a0.x); af[1] = (short)f2bf(a0.y);
    af[2] = (short)f2bf(a0.z); af[3] = (short)f2bf(a0.w);
    af[4] = (short)f2bf(a1.x); af[5] = (short)f2bf(a1.y);
    af[6] = (short)f2bf(a1.z); af[7] = (short)f2bf(a1.w);
    bf16x8 b0 = *(const bf16x8*)&otb[n16][ks * 32 + kg * 8];
    bf16x8 b1 = *(const bf16x8*)&otb[16 + n16][ks * 32 + kg * 8];
    acc[0] = __builtin_amdgcn_mfma_f32_16x16x32_bf16(af, b0, acc[0], 0, 0, 0);
    acc[1] = __builtin_amdgcn_mfma_f32_16x16x32_bf16(af, b1, acc[1], 0, 0, 0);
  }
  // D: col = lane&15 (l), row = kg*4+rg (c in 16-tile); rg = consecutive c.
#pragma unroll
  for (int l2 = 0; l2 < 2; ++l2) {
    float4 st = make_float4(acc[l2][0], acc[l2][1], acc[l2][2], acc[l2][3]);
    *(float4*)&s[OO2 + (size_t)(l0 + l2 * 16 + n16) * 64 + wid * 16 + kg * 4] = st;
  }
}

// 6.5. Weight prep: Wbf8[xcd 8][27][co 64][ci 64] bf16 at ws + bcnt*PER_B.
__global__ __launch_bounds__(256) void kprepw(
    const float* __restrict__ pw, float* __restrict__ wdst) {
  int off = blockIdx.x;
  u16* wb = (u16*)wdst;
  int tid = threadIdx.x;
  for (int i = tid; i < 4096; i += 256) {
    int co = i >> 6, ci = i & 63;
    u16 v = f2bf(pw[(size_t)(co * 64 + ci) * 27 + off]);
#pragma unroll
    for (int xc = 0; xc < 8; ++xc)
      wb[(size_t)xc * WB1 + off * 4096 + i] = v;
  }
}

// 7. conv3d (bf16 implicit GEMM on MFMA) + FUSED 1x1x1 norm mix. (R27 form.)
__global__ __launch_bounds__(256, 2) void kconv3(
    const float* __restrict__ pb, const float* __restrict__ nw,
    const float* __restrict__ nb, const float* __restrict__ xin,
    float* __restrict__ out, const u16* __restrict__ wb,
    float* __restrict__ ws, int b0) {
  int bi = blockIdx.y, gb = b0 + bi;
  float* s = ws + (size_t)bi * PER_B;
  int bx = blockIdx.x;
  int t = bx >> 3, hq = bx & 7;
  int h0 = hq * 2;
  int tid = threadIdx.x;
  const float* xr = s + OO2;              // o2 in c-major reshape view

  __shared__ u16 Xs[3 * 4 * 18 * 72];     // 31104 B; later aliased as cx
  float* cx = (float*)Xs;                 // cx[64][33] = 8448 B
  {
    u32* xz32 = (u32*)Xs;
    for (int i = tid; i < 3 * 4 * 18 * 72 / 2; i += 256) xz32[i] = 0u;
  }
  __syncthreads();
  {
    int ci = tid >> 2, wq = tid & 3;
#pragma unroll
    for (int rowc = 0; rowc < 12; ++rowc) {
      int tt = rowc >> 2, hh = rowc & 3;
      int ts = t + tt - 1, hs = h0 + hh - 1;
      if (ts < 0 || ts > 15 || hs < 0 || hs > 15) continue;
      float4 v = *(const float4*)(xr + (size_t)ci * NL + ts * 256 + hs * 16 + wq * 4);
      int rb = (tt * 4 + hh) * 18 + 1 + wq * 4;
      Xs[(rb + 0) * 72 + ci] = f2bf(v.x);
      Xs[(rb + 1) * 72 + ci] = f2bf(v.y);
      Xs[(rb + 2) * 72 + ci] = f2bf(v.z);
      Xs[(rb + 3) * 72 + ci] = f2bf(v.w);
    }
  }
  __syncthreads();

  int wid = tid >> 6, lane = tid & 63;
  int cq = wid;
  int n16 = lane & 15, kg = lane >> 4;
  f32x4 acc[2] = {};

  const u16* wbA = wb + (size_t)(bx & 7) * WB1 +
                   (size_t)(cq * 16 + n16) * 64 + kg * 8;
#pragma unroll
  for (int kt = 0; kt < 3; ++kt)
#pragma unroll
    for (int kh = 0; kh < 3; ++kh) {
#pragma unroll
      for (int kw = 0; kw < 3; ++kw) {
        int off = (kt * 3 + kh) * 3 + kw;
        const u16* pa = wbA + off * 4096;
#pragma unroll
        for (int st = 0; st < 2; ++st) {
          int kb = st * 32;
          bf16x8 a0 = *(const bf16x8*)(pa + kb);
#pragma unroll
          for (int l2 = 0; l2 < 2; ++l2) {
            int r = (kt * 4 + l2 + kh) * 18 + n16 + kw;
            bf16x8 b0 = *(const bf16x8*)(&Xs[r * 72 + kb + kg * 8]);
            acc[l2] = __builtin_amdgcn_mfma_f32_16x16x32_bf16(a0, b0, acc[l2], 0, 0, 0);
          }
        }
      }
    }
  __syncthreads();

#pragma unroll
  for (int l2 = 0; l2 < 2; ++l2) {
    int lp = l2 * 16 + n16;
    int lg = t * 256 + (h0 + l2) * 16 + n16;
#pragma unroll
    for (int rg = 0; rg < 4; ++rg) {
      int co = cq * 16 + kg * 4 + rg;
      cx[co * 33 + lp] = acc[l2][rg] + pb[co] +
                         xin[(size_t)(gb * 64 + co) * NL + lg];
    }
  }
  __syncthreads();

  {
    int co2 = tid >> 2, pq = tid & 3;
    float mac[8];
#pragma unroll
    for (int j = 0; j < 8; ++j) mac[j] = 0.f;
    for (int ci = 0; ci < 64; ci += 4) {
      float4 w4 = *(const float4*)&nw[co2 * 64 + ci];
      float wv[4] = {w4.x, w4.y, w4.z, w4.w};
#pragma unroll
      for (int cc = 0; cc < 4; ++cc) {
        const float* row = &cx[(ci + cc) * 33 + pq * 8];
        float4 a = *(const float4*)&row[0];
        float4 b = *(const float4*)&row[4];
        mac[0] = fmaf(wv[cc], a.x, mac[0]);  mac[1] = fmaf(wv[cc], a.y, mac[1]);
        mac[2] = fmaf(wv[cc], a.z, mac[2]);  mac[3] = fmaf(wv[cc], a.w, mac[3]);
        mac[4] = fmaf(wv[cc], b.x, mac[4]);  mac[5] = fmaf(wv[cc], b.y, mac[5]);
        mac[6] = fmaf(wv[cc], b.z, mac[6]);  mac[7] = fmaf(wv[cc], b.w, mac[7]);
      }
    }
    float bias = nb[co2];
    float4* dst = (float4*)(out + (size_t)(gb * 64 + co2) * NL +
                            t * 256 + h0 * 16 + pq * 8);
    dst[0] = make_float4(mac[0] + bias, mac[1] + bias, mac[2] + bias, mac[3] + bias);
    dst[1] = make_float4(mac[4] + bias, mac[5] + bias, mac[6] + bias, mac[7] + bias);
  }
}

// ---------------------------------------------------------------------------
extern "C" void kernel_launch(void* const* d_in, const int* in_sizes, int n_in,
                              void* d_out, int out_size, void* d_ws, size_t ws_size,
                              hipStream_t stream) {
  const float* x    = (const float*)d_in[0];
  const float* wip  = (const float*)d_in[1];
  const float* cwf  = (const float*)d_in[2];
  const float* cbf  = (const float*)d_in[3];
  const float* xpf  = (const float*)d_in[4];
  const float* dtwf = (const float*)d_in[5];
  const float* dtbf = (const float*)d_in[6];
  const float* Alf  = (const float*)d_in[7];
  const float* Df   = (const float*)d_in[8];
  const float* cwb  = (const float*)d_in[9];
  const float* cbb  = (const float*)d_in[10];
  const float* xpb  = (const float*)d_in[11];
  const float* dtwb = (const float*)d_in[12];
  const float* dtbb = (const float*)d_in[13];
  const float* Alb  = (const float*)d_in[14];
  const float* Db   = (const float*)d_in[15];
  const float* wout = (const float*)d_in[16];
  const float* pw   = (const float*)d_in[17];
  const float* pb   = (const float*)d_in[18];
  const float* nw   = (const float*)d_in[19];
  const float* nb   = (const float*)d_in[20];

  const size_t PER_B_BYTES = (size_t)PER_B * 4;  // 22,282,240 per batch slab
  const size_t WB_BYTES = 8u * WB1 * 2u;         // 1,769,472 (8 Wbf replicas)
  int bcnt;
  if (ws_size >= 4 * PER_B_BYTES + WB_BYTES) bcnt = 4;
  else if (ws_size >= PER_B_BYTES + WB_BYTES) bcnt = 1;
  else return;
  int passes = 4 / bcnt;

  float* ws = (float*)d_ws;
  float* wsW = ws + (size_t)bcnt * PER_B;
  kprepw<<<dim3(27), 256, 0, stream>>>(pw, wsW);
  for (int p = 0; p < passes; ++p) {
    int b0 = p * bcnt;
    kxz   <<<dim3(256, bcnt), 256, 0, stream>>>(x, wip, ws, b0);
    k2prep<<<dim3(256, bcnt), 256, 0, stream>>>(cwf, cbf, xpf, dtwf, dtbf,
                                                cwb, cbb, xpb, dtwb, dtbb, ws);
    kscanA<<<dim3(1024, bcnt), 256, 0, stream>>>(Alf, Alb, ws);
    kscanC<<<dim3(1024, bcnt), 256, 0, stream>>>(Alf, Df, Alb, Db, ws);
    koutg <<<dim3(128, bcnt), 256, 0, stream>>>(wout, ws);
    kconv3<<<dim3(128, bcnt), 256, 0, stream>>>(pb, nw, nb, x, (float*)d_out,
                                                (const u16*)wsW, ws, b0);
  }
}

// Round 14
// 254.179 us; speedup vs baseline: 1.0841x; 1.0141x over previous
//
#include <hip/hip_runtime.h>

// ---------------------------------------------------------------------------
// Bidirectional Mamba block, MI355X. Round 34:
//  - kscanA/kscanC: fold log2e into A (A2 = A*log2e at setup) and use raw
//    hardware exp2 (__builtin_amdgcn_exp2f) -> removes the v_mul(x,log2e)
//    hipcc emits inside every __expf, i.e. 1 full-rate VALU op per scan step
//    per chain (exp sequence was ~10 of ~36 issue cy/step).
//  - Otherwise identical to R33 (empirical best 257.77us): MFMA conv3/x_dbl/
//    outproj, knorm fusion, XCD-local weight replicas, fp32 scan streams,
//    kscanB eliminated, R28-form scans.
// Shapes: B=4, C=64, D=128, L=4096 (l = h*256 + w*16 + t), N=16, R=8.
// ---------------------------------------------------------------------------

#define NL 4096
#define LOG2E 1.4426950408889634f

typedef unsigned short u16;
typedef unsigned int u32;
typedef __attribute__((ext_vector_type(8))) short bf16x8;
typedef __attribute__((ext_vector_type(4))) float f32x4;

__device__ __forceinline__ float siluf_(float x) {
  return x * __builtin_amdgcn_rcpf(1.f + __expf(-x));
}
__device__ __forceinline__ float softplusf_(float x) {
  return (x > 20.f) ? x : __logf(1.f + __expf(x));
}
__device__ __forceinline__ u16 f2bf(float f) {
  u32 u = __float_as_uint(f);
  u += 0x7fffu + ((u >> 16) & 1u);
  return (u16)(u >> 16);
}

// Sum over the 16-lane DPP row via rotations 1,2,4,8 (VALU pipe, no DS).
__device__ __forceinline__ float rowsum16_(float p) {
  int q;
  q = __builtin_amdgcn_mov_dpp(__float_as_int(p), 0x121, 0xf, 0xf, false);
  p += __int_as_float(q);
  q = __builtin_amdgcn_mov_dpp(__float_as_int(p), 0x122, 0xf, 0xf, false);
  p += __int_as_float(q);
  q = __builtin_amdgcn_mov_dpp(__float_as_int(p), 0x124, 0xf, 0xf, false);
  p += __int_as_float(q);
  q = __builtin_amdgcn_mov_dpp(__float_as_int(p), 0x128, 0xf, 0xf, false);
  p += __int_as_float(q);
  return p;
}

// Per-b slab offsets (fp32 elements)
#define OXZ  0u          // xz [256][4096] fp32
#define OUCF 1048576u    // ucf [128][4096] fp32
#define OUCB 1572864u    // ucb [128][4096] fp32 (flipped coords)
#define ODLF 2424832u    // dlf [128][4096] fp32
#define ODLB 2949120u    // dlb [128][4096] fp32 (flipped coords)
#define OYF  3473408u    // yf [128][4096] fp32
#define OYB  3997696u    // yb [128][4096] fp32 (flipped coords)
#define OO   4521984u    // scan scratch: P [262144] S [262144] fp32
#define OO2  5046272u    // bct bf16 until kscanC; then o2 [4096][64] fp32
#define PER_B 5570560u
// Wbf8 [8 xcd][27][64][64] bf16 lives at ws + bcnt*PER_B

#define NCH 64   // scan chunks
#define CL  64   // chunk length
#define WB1 110592u  // u16 elems per Wbf copy (27*64*64)

// 1. xz[e,l] = sum_c in_proj_w[e,c] * seq[c,l].
__global__ __launch_bounds__(256) void kxz(
    const float* __restrict__ x, const float* __restrict__ wip,
    float* __restrict__ ws, int b0) {
  int bi = blockIdx.y, gb = b0 + bi;
  float* s = ws + (size_t)bi * PER_B;
  int bid = blockIdx.x;
  int h = bid >> 4, w = bid & 15;
  int tid = threadIdx.x;
  __shared__ float xs[64][16];
  for (int i = tid; i < 1024; i += 256) {
    int c = i >> 4, t = i & 15;
    xs[c][t] = x[(size_t)(gb * 64 + c) * NL + t * 256 + h * 16 + w];
  }
  __syncthreads();
  int e = tid;
  float acc[16];
#pragma unroll
  for (int t = 0; t < 16; ++t) acc[t] = 0.f;
  for (int c = 0; c < 64; ++c) {
    float wv = wip[e * 64 + c];
#pragma unroll
    for (int t = 0; t < 16; ++t) acc[t] = fmaf(wv, xs[c][t], acc[t]);
  }
  float4* dst = (float4*)(s + OXZ + (size_t)e * NL + h * 256 + w * 16);
#pragma unroll
  for (int q = 0; q < 4; ++q)
    dst[q] = make_float4(acc[q * 4], acc[q * 4 + 1], acc[q * 4 + 2], acc[q * 4 + 3]);
}

// 2. Fused prep per (bi, dir, 32-l tile): dwconv+silu, x_dbl via MFMA, delta,
// bct. Grid x = 256 (lt 128 x dir 2). uc/dl stored fp32.
__global__ __launch_bounds__(256) void k2prep(
    const float* __restrict__ cwf, const float* __restrict__ cbf,
    const float* __restrict__ xpf, const float* __restrict__ dtwf,
    const float* __restrict__ dtbf,
    const float* __restrict__ cwb, const float* __restrict__ cbb,
    const float* __restrict__ xpb, const float* __restrict__ dtwb,
    const float* __restrict__ dtbb,
    float* __restrict__ ws) {
  int bi = blockIdx.y;
  float* s = ws + (size_t)bi * PER_B;
  int bx = blockIdx.x;
  int lt = bx >> 1, dir = bx & 1;
  int l0 = lt * 32;
  int lout0 = dir ? (127 - lt) * 32 : l0;   // output base (flipped for bwd)
  int tid = threadIdx.x;

  __shared__ float pool[128 * 40];   // X[128][40] during dwconv; xds after
  __shared__ u16 uct[32][136];       // uc transposed bf16 (d-contig, 16B rows)
  float (*X)[40] = (float(*)[40])pool;

  for (int i = tid; i < 128 * 38; i += 256) {
    int d = i / 38, j = i - d * 38;
    int l = l0 - 3 + j;
    X[d][j] = (l >= 0 && l < NL) ? s[OXZ + (size_t)d * NL + l] : 0.f;
  }
  __syncthreads();

  const float* cw = dir ? cwb : cwf;
  const float* cb = dir ? cbb : cbf;
  float* ucg = s + (dir ? OUCB : OUCF);
  for (int i = tid; i < 128 * 32; i += 256) {
    int d = i >> 5, li = i & 31;
    float a = cb[d];
    if (dir == 0) {
#pragma unroll
      for (int k = 0; k < 4; ++k) a = fmaf(cw[d * 4 + k], X[d][li + k], a);
    } else {
#pragma unroll
      for (int k = 0; k < 4; ++k) a = fmaf(cw[d * 4 + k], X[d][37 - li - k], a);
    }
    a = siluf_(a);
    uct[li][d] = f2bf(a);
    ucg[(size_t)d * NL + lout0 + li] = a;
  }
  __syncthreads();  // X dead; pool becomes xds [40][33]

  // x_dbl via MFMA 16x16x32: D[e 48][l 32], K=128. Units (et,lt2) = 6 over
  // 4 waves (waves 0,1 take two units).
  float* xds = pool;
  {
    int wid = tid >> 6, lane = tid & 63;
    int n16 = lane & 15, kg = lane >> 4;
    const float* xp = dir ? xpb : xpf;
#pragma unroll
    for (int rep = 0; rep < 2; ++rep) {
      int id = wid + rep * 4;
      if (id < 6) {
        int et = id >> 1, lt2 = id & 1;
        f32x4 acc = {};
#pragma unroll
        for (int ks = 0; ks < 4; ++ks) {
          bf16x8 bfrag = *(const bf16x8*)&uct[lt2 * 16 + n16][ks * 32 + kg * 8];
          int e = et * 16 + n16;
          int ec = (e < 40) ? e : 39;        // clamp addr; rows >=40 discarded
          const float* pa = xp + ec * 128 + ks * 32 + kg * 8;
          float4 a0 = *(const float4*)pa;
          float4 a1 = *(const float4*)(pa + 4);
          bf16x8 af;
          af[0] = (short)f2bf(a0.x); af[1] = (short)f2bf(a0.y);
          af[2] = (short)f2bf(a0.z); af[3] = (short)f2bf(a0.w);
          af[4] = (short)f2bf(a1.x); af[5] = (short)f2bf(a1.y);
          af[6] = (short)f2bf(a1.z); af[7] = (short)f2bf(a1.w);
          acc = __builtin_amdgcn_mfma_f32_16x16x32_bf16(af, bfrag, acc, 0, 0, 0);
        }
        // D layout: col = lane&15 (l), row = kg*4 + rg (e within 16-tile)
#pragma unroll
        for (int rg = 0; rg < 4; ++rg) {
          int e = et * 16 + kg * 4 + rg;
          if (e < 40) xds[e * 33 + lt2 * 16 + n16] = acc[rg];
        }
      }
    }
  }
  __syncthreads();

  const float* dtw = dir ? dtwb : dtwf;
  const float* dtb = dir ? dtbb : dtbf;
  float* dlg = s + (dir ? ODLB : ODLF);
  for (int i = tid; i < 128 * 32; i += 256) {
    int d = i >> 5, li = i & 31;
    float pre = dtb[d];
#pragma unroll
    for (int r = 0; r < 8; ++r)
      pre = fmaf(dtw[d * 8 + r], xds[r * 33 + li], pre);
    dlg[(size_t)d * NL + lout0 + li] = softplusf_(pre);
  }
  u16* bctp = (u16*)(s + OO2);
  for (int i = tid; i < 32 * 32; i += 256) {
    int li = i >> 5, k = i & 31;
    bctp[((size_t)dir * 4096 + lout0 + li) * 32 + k] = f2bf(xds[(8 + k) * 33 + li]);
  }
}

// 5a. Phase A: 16 d-rows/block; B-half of chunk bct staged to fp32 LDS;
// fp32 dl/uc float4 loads; fully unrolled; exp2-folded A; P = exp2(A2*sum).
__global__ __launch_bounds__(256) void kscanA(
    const float* __restrict__ Alf, const float* __restrict__ Alb,
    float* __restrict__ ws) {
  int bi = blockIdx.y;
  float* s = ws + (size_t)bi * PER_B;
  int xid = blockIdx.x;
  int chunk = xid >> 4, dir = (xid >> 3) & 1, d8 = xid & 7;
  int tid = threadIdx.x;
  int wv = tid >> 6, lane = tid & 63;
  int n = lane & 15, g = lane >> 4;
  int d = d8 * 16 + wv * 4 + g;
  int l0 = chunk * CL;
  __shared__ float bl[CL * 16];
  {
    const u16* bctp = (const u16*)(s + OO2) + ((size_t)dir * 4096 + l0) * 32;
    for (int i = tid; i < CL * 16; i += 256) {
      int l = i >> 4, k = i & 15;
      bl[i] = __uint_as_float(((u32)bctp[l * 32 + k]) << 16);
    }
  }
  __syncthreads();
  const float* ucp = s + (dir ? OUCB : OUCF) + (size_t)d * NL + l0;
  const float* dlp = s + (dir ? ODLB : ODLF) + (size_t)d * NL + l0;
  const float* blB = bl + n;
  float A2 = -__expf((dir ? Alb : Alf)[d * 16 + n]) * LOG2E;
  float sdv = 0.f, S = 0.f;
#pragma unroll
  for (int i0 = 0; i0 < CL; i0 += 8) {
    float4 dq0 = *(const float4*)(dlp + i0);
    float4 dq1 = *(const float4*)(dlp + i0 + 4);
    float4 uq0 = *(const float4*)(ucp + i0);
    float4 uq1 = *(const float4*)(ucp + i0 + 4);
    float dv[8] = {dq0.x, dq0.y, dq0.z, dq0.w, dq1.x, dq1.y, dq1.z, dq1.w};
    float uv[8] = {uq0.x, uq0.y, uq0.z, uq0.w, uq1.x, uq1.y, uq1.z, uq1.w};
#pragma unroll
    for (int j = 0; j < 8; ++j) {
      float dA = __builtin_amdgcn_exp2f(dv[j] * A2);
      S = fmaf(dA, S, dv[j] * blB[(i0 + j) * 16] * uv[j]);
      sdv += dv[j];
    }
  }
  size_t cidx = ((size_t)(chunk * 2 + dir) * 128 + d) * 16 + n;
  s[OO + cidx] = __builtin_amdgcn_exp2f(A2 * sdv);
  s[OO + 262144u + cidx] = S;
}

// 5c. Phase C: self-seeded re-scan; fp32 dl/uc; fully unrolled; DPP row-sum;
// ps writes batched per 8 steps; exp2-folded A. (R28 structure.)
__global__ __launch_bounds__(256) void kscanC(
    const float* __restrict__ Alf, const float* __restrict__ Df,
    const float* __restrict__ Alb, const float* __restrict__ Db,
    float* __restrict__ ws) {
  int bi = blockIdx.y;
  float* s = ws + (size_t)bi * PER_B;
  int xid = blockIdx.x;
  int chunk = xid >> 4, dir = (xid >> 3) & 1, d8 = xid & 7;
  int tid = threadIdx.x;
  int wv = tid >> 6, lane = tid & 63;
  int n = lane & 15, g = lane >> 4;
  int d = d8 * 16 + wv * 4 + g;
  int l0 = chunk * CL;
  __shared__ float bl[CL * 32];
  __shared__ float ps[16][65];
  {
    const u16* bctp = (const u16*)(s + OO2) + ((size_t)dir * 4096 + l0) * 32;
    for (int i = tid; i < CL * 32; i += 256)
      bl[i] = __uint_as_float(((u32)bctp[i]) << 16);
  }
  __syncthreads();
  const float* ucp = s + (dir ? OUCB : OUCF) + (size_t)d * NL + l0;
  const float* dlp = s + (dir ? ODLB : ODLF) + (size_t)d * NL + l0;
  const float* blB = bl + n;
  float* ybase = s + (dir ? OYB : OYF);
  float A2 = -__expf((dir ? Alb : Alf)[d * 16 + n]) * LOG2E;
  float Dv = (dir ? Db : Df)[d];
  // Self-seed: fold P/S of chunks < chunk for this (dir, d, n).
  float h = 0.f;
  {
    size_t stepi = (size_t)d * 16 + n;
#pragma unroll 4
    for (int c = 0; c < chunk; ++c) {
      size_t idx = ((size_t)(c * 2 + dir) * 128) * 16 + stepi;
      float pv = s[OO + idx], sv = s[OO + 262144u + idx];
      h = fmaf(pv, h, sv);
    }
  }
  int prow = wv * 4 + g;
#pragma unroll
  for (int i0 = 0; i0 < CL; i0 += 8) {
    float4 dq0 = *(const float4*)(dlp + i0);
    float4 dq1 = *(const float4*)(dlp + i0 + 4);
    float4 uq0 = *(const float4*)(ucp + i0);
    float4 uq1 = *(const float4*)(ucp + i0 + 4);
    float dv[8] = {dq0.x, dq0.y, dq0.z, dq0.w, dq1.x, dq1.y, dq1.z, dq1.w};
    float uv[8] = {uq0.x, uq0.y, uq0.z, uq0.w, uq1.x, uq1.y, uq1.z, uq1.w};
    float yv[8];
#pragma unroll
    for (int j = 0; j < 8; ++j) {
      float dA = __builtin_amdgcn_exp2f(dv[j] * A2);
      h = fmaf(dA, h, dv[j] * blB[(i0 + j) * 32] * uv[j]);
      float p = rowsum16_(h * blB[(i0 + j) * 32 + 16]);
      yv[j] = fmaf(uv[j], Dv, p);
    }
    if (n == 0) {
#pragma unroll
      for (int j = 0; j < 8; ++j) ps[prow][i0 + j] = yv[j];
    }
  }
  __syncthreads();
  for (int i = tid; i < 16 * CL; i += 256) {
    int row = i >> 6, col = i & 63;
    ybase[(size_t)(d8 * 16 + row) * NL + l0 + col] = ps[row][col];
  }
}

// 6. Fused gate + out-proj via MFMA. Block = 32-l tile.
__global__ __launch_bounds__(256) void koutg(
    const float* __restrict__ wout, float* __restrict__ ws) {
  int bi = blockIdx.y;
  float* s = ws + (size_t)bi * PER_B;
  int lt = blockIdx.x;
  int l0 = lt * 32;
  int tid = threadIdx.x;
  __shared__ u16 otb[32][136];
  for (int i = tid; i < 128 * 32; i += 256) {
    int d = i >> 5, li = i & 31;
    int l = l0 + li;
    float z = s[OXZ + (size_t)(128 + d) * NL + l];
    float v = s[OYF + (size_t)d * NL + l] + s[OYB + (size_t)d * NL + (NL - 1 - l)];
    otb[li][d] = f2bf(v * siluf_(z));
  }
  __syncthreads();
  int wid = tid >> 6, lane = tid & 63;
  int n16 = lane & 15, kg = lane >> 4;
  f32x4 acc[2] = {};   // [l2 tile]
  const float* wr = wout + (size_t)(wid * 16 + n16) * 128 + kg * 8;
#pragma unroll
  for (int ks = 0; ks < 4; ++ks) {
    const float* pa = wr + ks * 32;
    float4 a0 = *(const float4*)pa;
    float4 a1 = *(const float4*)(pa + 4);
    bf16x8 af;
    af[0] = (short)f2bf(a0.x); af[1] = (short)f2bf(a0.y);
    af[2] = (short)f2bf(a0.z); af[3] = (short)f2bf(a0.w);
    af[4] = (short)f2bf(a1.x); af[5] = (short)f2bf(a1.y);
    af[6] = (short)f2bf(a1.z); af[7] = (short)f2bf(a1.w);
    bf16x8 b0 = *(const bf16x8*)&otb[n16][ks * 32 + kg * 8];
    bf16x8 b1 = *(const bf16x8*)&otb[16 + n16][ks * 32 + kg * 8];
    acc[0] = __builtin_amdgcn_mfma_f32_16x16x32_bf16(af, b0, acc[0], 0, 0, 0);
    acc[1] = __builtin_amdgcn_mfma_f32_16x16x32_bf16(af, b1, acc[1], 0, 0, 0);
  }
  // D: col = lane&15 (l), row = kg*4+rg (c in 16-tile); rg = consecutive c.
#pragma unroll
  for (int l2 = 0; l2 < 2; ++l2) {
    float4 st = make_float4(acc[l2][0], acc[l2][1], acc[l2][2], acc[l2][3]);
    *(float4*)&s[OO2 + (size_t)(l0 + l2 * 16 + n16) * 64 + wid * 16 + kg * 4] = st;
  }
}

// 6.5. Weight prep: Wbf8[xcd 8][27][co 64][ci 64] bf16 at ws + bcnt*PER_B.
__global__ __launch_bounds__(256) void kprepw(
    const float* __restrict__ pw, float* __restrict__ wdst) {
  int off = blockIdx.x;
  u16* wb = (u16*)wdst;
  int tid = threadIdx.x;
  for (int i = tid; i < 4096; i += 256) {
    int co = i >> 6, ci = i & 63;
    u16 v = f2bf(pw[(size_t)(co * 64 + ci) * 27 + off]);
#pragma unroll
    for (int xc = 0; xc < 8; ++xc)
      wb[(size_t)xc * WB1 + off * 4096 + i] = v;
  }
}

// 7. conv3d (bf16 implicit GEMM on MFMA) + FUSED 1x1x1 norm mix. (R27 form.)
__global__ __launch_bounds__(256, 2) void kconv3(
    const float* __restrict__ pb, const float* __restrict__ nw,
    const float* __restrict__ nb, const float* __restrict__ xin,
    float* __restrict__ out, const u16* __restrict__ wb,
    float* __restrict__ ws, int b0) {
  int bi = blockIdx.y, gb = b0 + bi;
  float* s = ws + (size_t)bi * PER_B;
  int bx = blockIdx.x;
  int t = bx >> 3, hq = bx & 7;
  int h0 = hq * 2;
  int tid = threadIdx.x;
  const float* xr = s + OO2;              // o2 in c-major reshape view

  __shared__ u16 Xs[3 * 4 * 18 * 72];     // 31104 B; later aliased as cx
  float* cx = (float*)Xs;                 // cx[64][33] = 8448 B
  {
    u32* xz32 = (u32*)Xs;
    for (int i = tid; i < 3 * 4 * 18 * 72 / 2; i += 256) xz32[i] = 0u;
  }
  __syncthreads();
  {
    int ci = tid >> 2, wq = tid & 3;
#pragma unroll
    for (int rowc = 0; rowc < 12; ++rowc) {
      int tt = rowc >> 2, hh = rowc & 3;
      int ts = t + tt - 1, hs = h0 + hh - 1;
      if (ts < 0 || ts > 15 || hs < 0 || hs > 15) continue;
      float4 v = *(const float4*)(xr + (size_t)ci * NL + ts * 256 + hs * 16 + wq * 4);
      int rb = (tt * 4 + hh) * 18 + 1 + wq * 4;
      Xs[(rb + 0) * 72 + ci] = f2bf(v.x);
      Xs[(rb + 1) * 72 + ci] = f2bf(v.y);
      Xs[(rb + 2) * 72 + ci] = f2bf(v.z);
      Xs[(rb + 3) * 72 + ci] = f2bf(v.w);
    }
  }
  __syncthreads();

  int wid = tid >> 6, lane = tid & 63;
  int cq = wid;
  int n16 = lane & 15, kg = lane >> 4;
  f32x4 acc[2] = {};

  const u16* wbA = wb + (size_t)(bx & 7) * WB1 +
                   (size_t)(cq * 16 + n16) * 64 + kg * 8;
#pragma unroll
  for (int kt = 0; kt < 3; ++kt)
#pragma unroll
    for (int kh = 0; kh < 3; ++kh) {
#pragma unroll
      for (int kw = 0; kw < 3; ++kw) {
        int off = (kt * 3 + kh) * 3 + kw;
        const u16* pa = wbA + off * 4096;
#pragma unroll
        for (int st = 0; st < 2; ++st) {
          int kb = st * 32;
          bf16x8 a0 = *(const bf16x8*)(pa + kb);
#pragma unroll
          for (int l2 = 0; l2 < 2; ++l2) {
            int r = (kt * 4 + l2 + kh) * 18 + n16 + kw;
            bf16x8 b0 = *(const bf16x8*)(&Xs[r * 72 + kb + kg * 8]);
            acc[l2] = __builtin_amdgcn_mfma_f32_16x16x32_bf16(a0, b0, acc[l2], 0, 0, 0);
          }
        }
      }
    }
  __syncthreads();

#pragma unroll
  for (int l2 = 0; l2 < 2; ++l2) {
    int lp = l2 * 16 + n16;
    int lg = t * 256 + (h0 + l2) * 16 + n16;
#pragma unroll
    for (int rg = 0; rg < 4; ++rg) {
      int co = cq * 16 + kg * 4 + rg;
      cx[co * 33 + lp] = acc[l2][rg] + pb[co] +
                         xin[(size_t)(gb * 64 + co) * NL + lg];
    }
  }
  __syncthreads();

  {
    int co2 = tid >> 2, pq = tid & 3;
    float mac[8];
#pragma unroll
    for (int j = 0; j < 8; ++j) mac[j] = 0.f;
    for (int ci = 0; ci < 64; ci += 4) {
      float4 w4 = *(const float4*)&nw[co2 * 64 + ci];
      float wv[4] = {w4.x, w4.y, w4.z, w4.w};
#pragma unroll
      for (int cc = 0; cc < 4; ++cc) {
        const float* row = &cx[(ci + cc) * 33 + pq * 8];
        float4 a = *(const float4*)&row[0];
        float4 b = *(const float4*)&row[4];
        mac[0] = fmaf(wv[cc], a.x, mac[0]);  mac[1] = fmaf(wv[cc], a.y, mac[1]);
        mac[2] = fmaf(wv[cc], a.z, mac[2]);  mac[3] = fmaf(wv[cc], a.w, mac[3]);
        mac[4] = fmaf(wv[cc], b.x, mac[4]);  mac[5] = fmaf(wv[cc], b.y, mac[5]);
        mac[6] = fmaf(wv[cc], b.z, mac[6]);  mac[7] = fmaf(wv[cc], b.w, mac[7]);
      }
    }
    float bias = nb[co2];
    float4* dst = (float4*)(out + (size_t)(gb * 64 + co2) * NL +
                            t * 256 + h0 * 16 + pq * 8);
    dst[0] = make_float4(mac[0] + bias, mac[1] + bias, mac[2] + bias, mac[3] + bias);
    dst[1] = make_float4(mac[4] + bias, mac[5] + bias, mac[6] + bias, mac[7] + bias);
  }
}

// ---------------------------------------------------------------------------
extern "C" void kernel_launch(void* const* d_in, const int* in_sizes, int n_in,
                              void* d_out, int out_size, void* d_ws, size_t ws_size,
                              hipStream_t stream) {
  const float* x    = (const float*)d_in[0];
  const float* wip  = (const float*)d_in[1];
  const float* cwf  = (const float*)d_in[2];
  const float* cbf  = (const float*)d_in[3];
  const float* xpf  = (const float*)d_in[4];
  const float* dtwf = (const float*)d_in[5];
  const float* dtbf = (const float*)d_in[6];
  const float* Alf  = (const float*)d_in[7];
  const float* Df   = (const float*)d_in[8];
  const float* cwb  = (const float*)d_in[9];
  const float* cbb  = (const float*)d_in[10];
  const float* xpb  = (const float*)d_in[11];
  const float* dtwb = (const float*)d_in[12];
  const float* dtbb = (const float*)d_in[13];
  const float* Alb  = (const float*)d_in[14];
  const float* Db   = (const float*)d_in[15];
  const float* wout = (const float*)d_in[16];
  const float* pw   = (const float*)d_in[17];
  const float* pb   = (const float*)d_in[18];
  const float* nw   = (const float*)d_in[19];
  const float* nb   = (const float*)d_in[20];

  const size_t PER_B_BYTES = (size_t)PER_B * 4;  // 22,282,240 per batch slab
  const size_t WB_BYTES = 8u * WB1 * 2u;         // 1,769,472 (8 Wbf replicas)
  int bcnt;
  if (ws_size >= 4 * PER_B_BYTES + WB_BYTES) bcnt = 4;
  else if (ws_size >= PER_B_BYTES + WB_BYTES) bcnt = 1;
  else return;
  int passes = 4 / bcnt;

  float* ws = (float*)d_ws;
  float* wsW = ws + (size_t)bcnt * PER_B;
  kprepw<<<dim3(27), 256, 0, stream>>>(pw, wsW);
  for (int p = 0; p < passes; ++p) {
    int b0 = p * bcnt;
    kxz   <<<dim3(256, bcnt), 256, 0, stream>>>(x, wip, ws, b0);
    k2prep<<<dim3(256, bcnt), 256, 0, stream>>>(cwf, cbf, xpf, dtwf, dtbf,
                                                cwb, cbb, xpb, dtwb, dtbb, ws);
    kscanA<<<dim3(1024, bcnt), 256, 0, stream>>>(Alf, Alb, ws);
    kscanC<<<dim3(1024, bcnt), 256, 0, stream>>>(Alf, Df, Alb, Db, ws);
    koutg <<<dim3(128, bcnt), 256, 0, stream>>>(wout, ws);
    kconv3<<<dim3(128, bcnt), 256, 0, stream>>>(pb, nw, nb, x, (float*)d_out,
                                                (const u16*)wsW, ws, b0);
  }
}

// Round 15
// 253.813 us; speedup vs baseline: 1.0857x; 1.0014x over previous
//
#include <hip/hip_runtime.h>

// ---------------------------------------------------------------------------
// Bidirectional Mamba block, MI355X. Round 35:
//  - kscanC rowsum: emit fused v_add_f32_dpp (1 inst/level) via inline asm
//    instead of mov_dpp + add (2 inst/level). Rowsum 8->4 ops of the ~16
//    per-step issue budget. Bit-identical math (same rotation network).
//    If GCNDPPCombine was already fusing, this is ISA-neutral.
//  - Otherwise identical to R34 (best: 254.18us): exp2-folded scans, MFMA
//    conv3/x_dbl/outproj, knorm fusion, XCD weight replicas, fp32 streams,
//    kscanB eliminated.
// Shapes: B=4, C=64, D=128, L=4096 (l = h*256 + w*16 + t), N=16, R=8.
// ---------------------------------------------------------------------------

#define NL 4096
#define LOG2E 1.4426950408889634f

typedef unsigned short u16;
typedef unsigned int u32;
typedef __attribute__((ext_vector_type(8))) short bf16x8;
typedef __attribute__((ext_vector_type(4))) float f32x4;

__device__ __forceinline__ float siluf_(float x) {
  return x * __builtin_amdgcn_rcpf(1.f + __expf(-x));
}
__device__ __forceinline__ float softplusf_(float x) {
  return (x > 20.f) ? x : __logf(1.f + __expf(x));
}
__device__ __forceinline__ u16 f2bf(float f) {
  u32 u = __float_as_uint(f);
  u += 0x7fffu + ((u >> 16) & 1u);
  return (u16)(u >> 16);
}

// Sum over the 16-lane DPP row via FUSED v_add_f32_dpp rotations 1,2,4,8.
__device__ __forceinline__ float rowsum16_(float p) {
  float t;
  asm("v_add_f32_dpp %0, %1, %1 row_ror:1 row_mask:0xf bank_mask:0xf"
      : "=v"(t) : "v"(p));
  asm("v_add_f32_dpp %0, %1, %1 row_ror:2 row_mask:0xf bank_mask:0xf"
      : "=v"(p) : "v"(t));
  asm("v_add_f32_dpp %0, %1, %1 row_ror:4 row_mask:0xf bank_mask:0xf"
      : "=v"(t) : "v"(p));
  asm("v_add_f32_dpp %0, %1, %1 row_ror:8 row_mask:0xf bank_mask:0xf"
      : "=v"(p) : "v"(t));
  return p;
}

// Per-b slab offsets (fp32 elements)
#define OXZ  0u          // xz [256][4096] fp32
#define OUCF 1048576u    // ucf [128][4096] fp32
#define OUCB 1572864u    // ucb [128][4096] fp32 (flipped coords)
#define ODLF 2424832u    // dlf [128][4096] fp32
#define ODLB 2949120u    // dlb [128][4096] fp32 (flipped coords)
#define OYF  3473408u    // yf [128][4096] fp32
#define OYB  3997696u    // yb [128][4096] fp32 (flipped coords)
#define OO   4521984u    // scan scratch: P [262144] S [262144] fp32
#define OO2  5046272u    // bct bf16 until kscanC; then o2 [4096][64] fp32
#define PER_B 5570560u
// Wbf8 [8 xcd][27][64][64] bf16 lives at ws + bcnt*PER_B

#define NCH 64   // scan chunks
#define CL  64   // chunk length
#define WB1 110592u  // u16 elems per Wbf copy (27*64*64)

// 1. xz[e,l] = sum_c in_proj_w[e,c] * seq[c,l].
__global__ __launch_bounds__(256) void kxz(
    const float* __restrict__ x, const float* __restrict__ wip,
    float* __restrict__ ws, int b0) {
  int bi = blockIdx.y, gb = b0 + bi;
  float* s = ws + (size_t)bi * PER_B;
  int bid = blockIdx.x;
  int h = bid >> 4, w = bid & 15;
  int tid = threadIdx.x;
  __shared__ float xs[64][16];
  for (int i = tid; i < 1024; i += 256) {
    int c = i >> 4, t = i & 15;
    xs[c][t] = x[(size_t)(gb * 64 + c) * NL + t * 256 + h * 16 + w];
  }
  __syncthreads();
  int e = tid;
  float acc[16];
#pragma unroll
  for (int t = 0; t < 16; ++t) acc[t] = 0.f;
  for (int c = 0; c < 64; ++c) {
    float wv = wip[e * 64 + c];
#pragma unroll
    for (int t = 0; t < 16; ++t) acc[t] = fmaf(wv, xs[c][t], acc[t]);
  }
  float4* dst = (float4*)(s + OXZ + (size_t)e * NL + h * 256 + w * 16);
#pragma unroll
  for (int q = 0; q < 4; ++q)
    dst[q] = make_float4(acc[q * 4], acc[q * 4 + 1], acc[q * 4 + 2], acc[q * 4 + 3]);
}

// 2. Fused prep per (bi, dir, 32-l tile): dwconv+silu, x_dbl via MFMA, delta,
// bct. Grid x = 256 (lt 128 x dir 2). uc/dl stored fp32.
__global__ __launch_bounds__(256) void k2prep(
    const float* __restrict__ cwf, const float* __restrict__ cbf,
    const float* __restrict__ xpf, const float* __restrict__ dtwf,
    const float* __restrict__ dtbf,
    const float* __restrict__ cwb, const float* __restrict__ cbb,
    const float* __restrict__ xpb, const float* __restrict__ dtwb,
    const float* __restrict__ dtbb,
    float* __restrict__ ws) {
  int bi = blockIdx.y;
  float* s = ws + (size_t)bi * PER_B;
  int bx = blockIdx.x;
  int lt = bx >> 1, dir = bx & 1;
  int l0 = lt * 32;
  int lout0 = dir ? (127 - lt) * 32 : l0;   // output base (flipped for bwd)
  int tid = threadIdx.x;

  __shared__ float pool[128 * 40];   // X[128][40] during dwconv; xds after
  __shared__ u16 uct[32][136];       // uc transposed bf16 (d-contig, 16B rows)
  float (*X)[40] = (float(*)[40])pool;

  for (int i = tid; i < 128 * 38; i += 256) {
    int d = i / 38, j = i - d * 38;
    int l = l0 - 3 + j;
    X[d][j] = (l >= 0 && l < NL) ? s[OXZ + (size_t)d * NL + l] : 0.f;
  }
  __syncthreads();

  const float* cw = dir ? cwb : cwf;
  const float* cb = dir ? cbb : cbf;
  float* ucg = s + (dir ? OUCB : OUCF);
  for (int i = tid; i < 128 * 32; i += 256) {
    int d = i >> 5, li = i & 31;
    float a = cb[d];
    if (dir == 0) {
#pragma unroll
      for (int k = 0; k < 4; ++k) a = fmaf(cw[d * 4 + k], X[d][li + k], a);
    } else {
#pragma unroll
      for (int k = 0; k < 4; ++k) a = fmaf(cw[d * 4 + k], X[d][37 - li - k], a);
    }
    a = siluf_(a);
    uct[li][d] = f2bf(a);
    ucg[(size_t)d * NL + lout0 + li] = a;
  }
  __syncthreads();  // X dead; pool becomes xds [40][33]

  // x_dbl via MFMA 16x16x32: D[e 48][l 32], K=128. Units (et,lt2) = 6 over
  // 4 waves (waves 0,1 take two units).
  float* xds = pool;
  {
    int wid = tid >> 6, lane = tid & 63;
    int n16 = lane & 15, kg = lane >> 4;
    const float* xp = dir ? xpb : xpf;
#pragma unroll
    for (int rep = 0; rep < 2; ++rep) {
      int id = wid + rep * 4;
      if (id < 6) {
        int et = id >> 1, lt2 = id & 1;
        f32x4 acc = {};
#pragma unroll
        for (int ks = 0; ks < 4; ++ks) {
          bf16x8 bfrag = *(const bf16x8*)&uct[lt2 * 16 + n16][ks * 32 + kg * 8];
          int e = et * 16 + n16;
          int ec = (e < 40) ? e : 39;        // clamp addr; rows >=40 discarded
          const float* pa = xp + ec * 128 + ks * 32 + kg * 8;
          float4 a0 = *(const float4*)pa;
          float4 a1 = *(const float4*)(pa + 4);
          bf16x8 af;
          af[0] = (short)f2bf(a0.x); af[1] = (short)f2bf(a0.y);
          af[2] = (short)f2bf(a0.z); af[3] = (short)f2bf(a0.w);
          af[4] = (short)f2bf(a1.x); af[5] = (short)f2bf(a1.y);
          af[6] = (short)f2bf(a1.z); af[7] = (short)f2bf(a1.w);
          acc = __builtin_amdgcn_mfma_f32_16x16x32_bf16(af, bfrag, acc, 0, 0, 0);
        }
        // D layout: col = lane&15 (l), row = kg*4 + rg (e within 16-tile)
#pragma unroll
        for (int rg = 0; rg < 4; ++rg) {
          int e = et * 16 + kg * 4 + rg;
          if (e < 40) xds[e * 33 + lt2 * 16 + n16] = acc[rg];
        }
      }
    }
  }
  __syncthreads();

  const float* dtw = dir ? dtwb : dtwf;
  const float* dtb = dir ? dtbb : dtbf;
  float* dlg = s + (dir ? ODLB : ODLF);
  for (int i = tid; i < 128 * 32; i += 256) {
    int d = i >> 5, li = i & 31;
    float pre = dtb[d];
#pragma unroll
    for (int r = 0; r < 8; ++r)
      pre = fmaf(dtw[d * 8 + r], xds[r * 33 + li], pre);
    dlg[(size_t)d * NL + lout0 + li] = softplusf_(pre);
  }
  u16* bctp = (u16*)(s + OO2);
  for (int i = tid; i < 32 * 32; i += 256) {
    int li = i >> 5, k = i & 31;
    bctp[((size_t)dir * 4096 + lout0 + li) * 32 + k] = f2bf(xds[(8 + k) * 33 + li]);
  }
}

// 5a. Phase A: 16 d-rows/block; B-half of chunk bct staged to fp32 LDS;
// fp32 dl/uc float4 loads; fully unrolled; exp2-folded A; P = exp2(A2*sum).
__global__ __launch_bounds__(256) void kscanA(
    const float* __restrict__ Alf, const float* __restrict__ Alb,
    float* __restrict__ ws) {
  int bi = blockIdx.y;
  float* s = ws + (size_t)bi * PER_B;
  int xid = blockIdx.x;
  int chunk = xid >> 4, dir = (xid >> 3) & 1, d8 = xid & 7;
  int tid = threadIdx.x;
  int wv = tid >> 6, lane = tid & 63;
  int n = lane & 15, g = lane >> 4;
  int d = d8 * 16 + wv * 4 + g;
  int l0 = chunk * CL;
  __shared__ float bl[CL * 16];
  {
    const u16* bctp = (const u16*)(s + OO2) + ((size_t)dir * 4096 + l0) * 32;
    for (int i = tid; i < CL * 16; i += 256) {
      int l = i >> 4, k = i & 15;
      bl[i] = __uint_as_float(((u32)bctp[l * 32 + k]) << 16);
    }
  }
  __syncthreads();
  const float* ucp = s + (dir ? OUCB : OUCF) + (size_t)d * NL + l0;
  const float* dlp = s + (dir ? ODLB : ODLF) + (size_t)d * NL + l0;
  const float* blB = bl + n;
  float A2 = -__expf((dir ? Alb : Alf)[d * 16 + n]) * LOG2E;
  float sdv = 0.f, S = 0.f;
#pragma unroll
  for (int i0 = 0; i0 < CL; i0 += 8) {
    float4 dq0 = *(const float4*)(dlp + i0);
    float4 dq1 = *(const float4*)(dlp + i0 + 4);
    float4 uq0 = *(const float4*)(ucp + i0);
    float4 uq1 = *(const float4*)(ucp + i0 + 4);
    float dv[8] = {dq0.x, dq0.y, dq0.z, dq0.w, dq1.x, dq1.y, dq1.z, dq1.w};
    float uv[8] = {uq0.x, uq0.y, uq0.z, uq0.w, uq1.x, uq1.y, uq1.z, uq1.w};
#pragma unroll
    for (int j = 0; j < 8; ++j) {
      float dA = __builtin_amdgcn_exp2f(dv[j] * A2);
      S = fmaf(dA, S, dv[j] * blB[(i0 + j) * 16] * uv[j]);
      sdv += dv[j];
    }
  }
  size_t cidx = ((size_t)(chunk * 2 + dir) * 128 + d) * 16 + n;
  s[OO + cidx] = __builtin_amdgcn_exp2f(A2 * sdv);
  s[OO + 262144u + cidx] = S;
}

// 5c. Phase C: self-seeded re-scan; fp32 dl/uc; fully unrolled; fused-DPP
// row-sum; ps writes batched per 8 steps; exp2-folded A. (R28 structure.)
__global__ __launch_bounds__(256) void kscanC(
    const float* __restrict__ Alf, const float* __restrict__ Df,
    const float* __restrict__ Alb, const float* __restrict__ Db,
    float* __restrict__ ws) {
  int bi = blockIdx.y;
  float* s = ws + (size_t)bi * PER_B;
  int xid = blockIdx.x;
  int chunk = xid >> 4, dir = (xid >> 3) & 1, d8 = xid & 7;
  int tid = threadIdx.x;
  int wv = tid >> 6, lane = tid & 63;
  int n = lane & 15, g = lane >> 4;
  int d = d8 * 16 + wv * 4 + g;
  int l0 = chunk * CL;
  __shared__ float bl[CL * 32];
  __shared__ float ps[16][65];
  {
    const u16* bctp = (const u16*)(s + OO2) + ((size_t)dir * 4096 + l0) * 32;
    for (int i = tid; i < CL * 32; i += 256)
      bl[i] = __uint_as_float(((u32)bctp[i]) << 16);
  }
  __syncthreads();
  const float* ucp = s + (dir ? OUCB : OUCF) + (size_t)d * NL + l0;
  const float* dlp = s + (dir ? ODLB : ODLF) + (size_t)d * NL + l0;
  const float* blB = bl + n;
  float* ybase = s + (dir ? OYB : OYF);
  float A2 = -__expf((dir ? Alb : Alf)[d * 16 + n]) * LOG2E;
  float Dv = (dir ? Db : Df)[d];
  // Self-seed: fold P/S of chunks < chunk for this (dir, d, n).
  float h = 0.f;
  {
    size_t stepi = (size_t)d * 16 + n;
#pragma unroll 4
    for (int c = 0; c < chunk; ++c) {
      size_t idx = ((size_t)(c * 2 + dir) * 128) * 16 + stepi;
      float pv = s[OO + idx], sv = s[OO + 262144u + idx];
      h = fmaf(pv, h, sv);
    }
  }
  int prow = wv * 4 + g;
#pragma unroll
  for (int i0 = 0; i0 < CL; i0 += 8) {
    float4 dq0 = *(const float4*)(dlp + i0);
    float4 dq1 = *(const float4*)(dlp + i0 + 4);
    float4 uq0 = *(const float4*)(ucp + i0);
    float4 uq1 = *(const float4*)(ucp + i0 + 4);
    float dv[8] = {dq0.x, dq0.y, dq0.z, dq0.w, dq1.x, dq1.y, dq1.z, dq1.w};
    float uv[8] = {uq0.x, uq0.y, uq0.z, uq0.w, uq1.x, uq1.y, uq1.z, uq1.w};
    float yv[8];
#pragma unroll
    for (int j = 0; j < 8; ++j) {
      float dA = __builtin_amdgcn_exp2f(dv[j] * A2);
      h = fmaf(dA, h, dv[j] * blB[(i0 + j) * 32] * uv[j]);
      float p = rowsum16_(h * blB[(i0 + j) * 32 + 16]);
      yv[j] = fmaf(uv[j], Dv, p);
    }
    if (n == 0) {
#pragma unroll
      for (int j = 0; j < 8; ++j) ps[prow][i0 + j] = yv[j];
    }
  }
  __syncthreads();
  for (int i = tid; i < 16 * CL; i += 256) {
    int row = i >> 6, col = i & 63;
    ybase[(size_t)(d8 * 16 + row) * NL + l0 + col] = ps[row][col];
  }
}

// 6. Fused gate + out-proj via MFMA. Block = 32-l tile.
__global__ __launch_bounds__(256) void koutg(
    const float* __restrict__ wout, float* __restrict__ ws) {
  int bi = blockIdx.y;
  float* s = ws + (size_t)bi * PER_B;
  int lt = blockIdx.x;
  int l0 = lt * 32;
  int tid = threadIdx.x;
  __shared__ u16 otb[32][136];
  for (int i = tid; i < 128 * 32; i += 256) {
    int d = i >> 5, li = i & 31;
    int l = l0 + li;
    float z = s[OXZ + (size_t)(128 + d) * NL + l];
    float v = s[OYF + (size_t)d * NL + l] + s[OYB + (size_t)d * NL + (NL - 1 - l)];
    otb[li][d] = f2bf(v * siluf_(z));
  }
  __syncthreads();
  int wid = tid >> 6, lane = tid & 63;
  int n16 = lane & 15, kg = lane >> 4;
  f32x4 acc[2] = {};   // [l2 tile]
  const float* wr = wout + (size_t)(wid * 16 + n16) * 128 + kg * 8;
#pragma unroll
  for (int ks = 0; ks < 4; ++ks) {
    const float* pa = wr + ks * 32;
    float4 a0 = *(const float4*)pa;
    float4 a1 = *(const float4*)(pa + 4);
    bf16x8 af;
    af[0] = (short)f2bf(a0.x); af[1] = (short)f2bf(a0.y);
    af[2] = (short)f2bf(a0.z); af[3] = (short)f2bf(a0.w);
    af[4] = (short)f2bf(a1.x); af[5] = (short)f2bf(a1.y);
    af[6] = (short)f2bf(a1.z); af[7] = (short)f2bf(a1.w);
    bf16x8 b0 = *(const bf16x8*)&otb[n16][ks * 32 + kg * 8];
    bf16x8 b1 = *(const bf16x8*)&otb[16 + n16][ks * 32 + kg * 8];
    acc[0] = __builtin_amdgcn_mfma_f32_16x16x32_bf16(af, b0, acc[0], 0, 0, 0);
    acc[1] = __builtin_amdgcn_mfma_f32_16x16x32_bf16(af, b1, acc[1], 0, 0, 0);
  }
  // D: col = lane&15 (l), row = kg*4+rg (c in 16-tile); rg = consecutive c.
#pragma unroll
  for (int l2 = 0; l2 < 2; ++l2) {
    float4 st = make_float4(acc[l2][0], acc[l2][1], acc[l2][2], acc[l2][3]);
    *(float4*)&s[OO2 + (size_t)(l0 + l2 * 16 + n16) * 64 + wid * 16 + kg * 4] = st;
  }
}

// 6.5. Weight prep: Wbf8[xcd 8][27][co 64][ci 64] bf16 at ws + bcnt*PER_B.
__global__ __launch_bounds__(256) void kprepw(
    const float* __restrict__ pw, float* __restrict__ wdst) {
  int off = blockIdx.x;
  u16* wb = (u16*)wdst;
  int tid = threadIdx.x;
  for (int i = tid; i < 4096; i += 256) {
    int co = i >> 6, ci = i & 63;
    u16 v = f2bf(pw[(size_t)(co * 64 + ci) * 27 + off]);
#pragma unroll
    for (int xc = 0; xc < 8; ++xc)
      wb[(size_t)xc * WB1 + off * 4096 + i] = v;
  }
}

// 7. conv3d (bf16 implicit GEMM on MFMA) + FUSED 1x1x1 norm mix. (R27 form.)
__global__ __launch_bounds__(256, 2) void kconv3(
    const float* __restrict__ pb, const float* __restrict__ nw,
    const float* __restrict__ nb, const float* __restrict__ xin,
    float* __restrict__ out, const u16* __restrict__ wb,
    float* __restrict__ ws, int b0) {
  int bi = blockIdx.y, gb = b0 + bi;
  float* s = ws + (size_t)bi * PER_B;
  int bx = blockIdx.x;
  int t = bx >> 3, hq = bx & 7;
  int h0 = hq * 2;
  int tid = threadIdx.x;
  const float* xr = s + OO2;              // o2 in c-major reshape view

  __shared__ u16 Xs[3 * 4 * 18 * 72];     // 31104 B; later aliased as cx
  float* cx = (float*)Xs;                 // cx[64][33] = 8448 B
  {
    u32* xz32 = (u32*)Xs;
    for (int i = tid; i < 3 * 4 * 18 * 72 / 2; i += 256) xz32[i] = 0u;
  }
  __syncthreads();
  {
    int ci = tid >> 2, wq = tid & 3;
#pragma unroll
    for (int rowc = 0; rowc < 12; ++rowc) {
      int tt = rowc >> 2, hh = rowc & 3;
      int ts = t + tt - 1, hs = h0 + hh - 1;
      if (ts < 0 || ts > 15 || hs < 0 || hs > 15) continue;
      float4 v = *(const float4*)(xr + (size_t)ci * NL + ts * 256 + hs * 16 + wq * 4);
      int rb = (tt * 4 + hh) * 18 + 1 + wq * 4;
      Xs[(rb + 0) * 72 + ci] = f2bf(v.x);
      Xs[(rb + 1) * 72 + ci] = f2bf(v.y);
      Xs[(rb + 2) * 72 + ci] = f2bf(v.z);
      Xs[(rb + 3) * 72 + ci] = f2bf(v.w);
    }
  }
  __syncthreads();

  int wid = tid >> 6, lane = tid & 63;
  int cq = wid;
  int n16 = lane & 15, kg = lane >> 4;
  f32x4 acc[2] = {};

  const u16* wbA = wb + (size_t)(bx & 7) * WB1 +
                   (size_t)(cq * 16 + n16) * 64 + kg * 8;
#pragma unroll
  for (int kt = 0; kt < 3; ++kt)
#pragma unroll
    for (int kh = 0; kh < 3; ++kh) {
#pragma unroll
      for (int kw = 0; kw < 3; ++kw) {
        int off = (kt * 3 + kh) * 3 + kw;
        const u16* pa = wbA + off * 4096;
#pragma unroll
        for (int st = 0; st < 2; ++st) {
          int kb = st * 32;
          bf16x8 a0 = *(const bf16x8*)(pa + kb);
#pragma unroll
          for (int l2 = 0; l2 < 2; ++l2) {
            int r = (kt * 4 + l2 + kh) * 18 + n16 + kw;
            bf16x8 b0 = *(const bf16x8*)(&Xs[r * 72 + kb + kg * 8]);
            acc[l2] = __builtin_amdgcn_mfma_f32_16x16x32_bf16(a0, b0, acc[l2], 0, 0, 0);
          }
        }
      }
    }
  __syncthreads();

#pragma unroll
  for (int l2 = 0; l2 < 2; ++l2) {
    int lp = l2 * 16 + n16;
    int lg = t * 256 + (h0 + l2) * 16 + n16;
#pragma unroll
    for (int rg = 0; rg < 4; ++rg) {
      int co = cq * 16 + kg * 4 + rg;
      cx[co * 33 + lp] = acc[l2][rg] + pb[co] +
                         xin[(size_t)(gb * 64 + co) * NL + lg];
    }
  }
  __syncthreads();

  {
    int co2 = tid >> 2, pq = tid & 3;
    float mac[8];
#pragma unroll
    for (int j = 0; j < 8; ++j) mac[j] = 0.f;
    for (int ci = 0; ci < 64; ci += 4) {
      float4 w4 = *(const float4*)&nw[co2 * 64 + ci];
      float wv[4] = {w4.x, w4.y, w4.z, w4.w};
#pragma unroll
      for (int cc = 0; cc < 4; ++cc) {
        const float* row = &cx[(ci + cc) * 33 + pq * 8];
        float4 a = *(const float4*)&row[0];
        float4 b = *(const float4*)&row[4];
        mac[0] = fmaf(wv[cc], a.x, mac[0]);  mac[1] = fmaf(wv[cc], a.y, mac[1]);
        mac[2] = fmaf(wv[cc], a.z, mac[2]);  mac[3] = fmaf(wv[cc], a.w, mac[3]);
        mac[4] = fmaf(wv[cc], b.x, mac[4]);  mac[5] = fmaf(wv[cc], b.y, mac[5]);
        mac[6] = fmaf(wv[cc], b.z, mac[6]);  mac[7] = fmaf(wv[cc], b.w, mac[7]);
      }
    }
    float bias = nb[co2];
    float4* dst = (float4*)(out + (size_t)(gb * 64 + co2) * NL +
                            t * 256 + h0 * 16 + pq * 8);
    dst[0] = make_float4(mac[0] + bias, mac[1] + bias, mac[2] + bias, mac[3] + bias);
    dst[1] = make_float4(mac[4] + bias, mac[5] + bias, mac[6] + bias, mac[7] + bias);
  }
}

// ---------------------------------------------------------------------------
extern "C" void kernel_launch(void* const* d_in, const int* in_sizes, int n_in,
                              void* d_out, int out_size, void* d_ws, size_t ws_size,
                              hipStream_t stream) {
  const float* x    = (const float*)d_in[0];
  const float* wip  = (const float*)d_in[1];
  const float* cwf  = (const float*)d_in[2];
  const float* cbf  = (const float*)d_in[3];
  const float* xpf  = (const float*)d_in[4];
  const float* dtwf = (const float*)d_in[5];
  const float* dtbf = (const float*)d_in[6];
  const float* Alf  = (const float*)d_in[7];
  const float* Df   = (const float*)d_in[8];
  const float* cwb  = (const float*)d_in[9];
  const float* cbb  = (const float*)d_in[10];
  const float* xpb  = (const float*)d_in[11];
  const float* dtwb = (const float*)d_in[12];
  const float* dtbb = (const float*)d_in[13];
  const float* Alb  = (const float*)d_in[14];
  const float* Db   = (const float*)d_in[15];
  const float* wout = (const float*)d_in[16];
  const float* pw   = (const float*)d_in[17];
  const float* pb   = (const float*)d_in[18];
  const float* nw   = (const float*)d_in[19];
  const float* nb   = (const float*)d_in[20];

  const size_t PER_B_BYTES = (size_t)PER_B * 4;  // 22,282,240 per batch slab
  const size_t WB_BYTES = 8u * WB1 * 2u;         // 1,769,472 (8 Wbf replicas)
  int bcnt;
  if (ws_size >= 4 * PER_B_BYTES + WB_BYTES) bcnt = 4;
  else if (ws_size >= PER_B_BYTES + WB_BYTES) bcnt = 1;
  else return;
  int passes = 4 / bcnt;

  float* ws = (float*)d_ws;
  float* wsW = ws + (size_t)bcnt * PER_B;
  kprepw<<<dim3(27), 256, 0, stream>>>(pw, wsW);
  for (int p = 0; p < passes; ++p) {
    int b0 = p * bcnt;
    kxz   <<<dim3(256, bcnt), 256, 0, stream>>>(x, wip, ws, b0);
    k2prep<<<dim3(256, bcnt), 256, 0, stream>>>(cwf, cbf, xpf, dtwf, dtbf,
                                                cwb, cbb, xpb, dtwb, dtbb, ws);
    kscanA<<<dim3(1024, bcnt), 256, 0, stream>>>(Alf, Alb, ws);
    kscanC<<<dim3(1024, bcnt), 256, 0, stream>>>(Alf, Df, Alb, Db, ws);
    koutg <<<dim3(128, bcnt), 256, 0, stream>>>(wout, ws);
    kconv3<<<dim3(128, bcnt), 256, 0, stream>>>(pb, nw, nb, x, (float*)d_out,
                                                (const u16*)wsW, ws, b0);
  }
}